// Round 7
// baseline (393.224 us; speedup 1.0000x reference)
//
#include <hip/hip_runtime.h>

// RGCN 2-layer hetero graph conv. fp32 I/O, bf16 MFMA compute.
// R7: fuse gather-max into the GEMM. Per 64-row block: phase 1 gathers the
// relation segmax results into a swizzled LDS tile (byte ^= (row&7)<<4, G4/T2
// pattern, applied on both write and read); phase 2 runs the 4-wave MFMA GEMM
// with LDS A-operands. Kills the S_* buffers (128 MB/layer of HBM round-trip)
// and 2 dispatches. CSR build: zero-global-atomic 2-level MSD bucket sort (R6).

#define DI 128
#define NP 100000
#define NA 50000
#define EPB 4096
#define MAXBIN 391

typedef short s8v __attribute__((ext_vector_type(8)));
typedef float f32x4 __attribute__((ext_vector_type(4)));

__device__ __forceinline__ unsigned short bf16_rne(float f) {
  unsigned int fb = __float_as_uint(f);
  fb += 0x7FFFu + ((fb >> 16) & 1u);
  return (unsigned short)(fb >> 16);
}

// ---- fp32 -> bf16, both tables in one dispatch ----
__global__ __launch_bounds__(256) void cvt2_k(const float* __restrict__ Xp,
                                              unsigned short* __restrict__ Yp, int n4p,
                                              const float* __restrict__ Xa,
                                              unsigned short* __restrict__ Ya, int n4a) {
  int i = blockIdx.x * 256 + threadIdx.x;
  const float* X; unsigned short* Y;
  if (i < n4p) { X = Xp; Y = Yp; }
  else { i -= n4p; if (i >= n4a) return; X = Xa; Y = Ya; }
  float4 f = reinterpret_cast<const float4*>(X)[i];
  ushort4 o;
  o.x = bf16_rne(f.x); o.y = bf16_rne(f.y); o.z = bf16_rne(f.z); o.w = bf16_rne(f.w);
  reinterpret_cast<ushort4*>(Y)[i] = o;
}

// ==== radix CSR build (3 edge types via blockIdx.y) ====
struct R3Args {
  const int* src[3]; const int* dst[3];
  int* bh[3]; int* bhs[3];
  unsigned int* tmp[3];
  int* bkt[3]; int* cnt[3]; int* rs[3];
  int E[3]; int N[3]; int nbin[3]; int NB[3];
};

__global__ __launch_bounds__(256) void radix_s1_k(R3Args a) {
  int y = blockIdx.y, blk = blockIdx.x;
  int NB = a.NB[y];
  if (blk >= NB) return;
  __shared__ int hist[MAXBIN];
  int nbin = a.nbin[y];
  for (int i = threadIdx.x; i < nbin; i += 256) hist[i] = 0;
  __syncthreads();
  int e0 = blk * EPB, e1 = min(e0 + EPB, a.E[y]);
  const int* dst = a.dst[y];
  for (int e = e0 + threadIdx.x; e < e1; e += 256)
    atomicAdd(&hist[dst[e] >> 8], 1);
  __syncthreads();
  int* bh = a.bh[y];
  for (int i = threadIdx.x; i < nbin; i += 256) bh[i * NB + blk] = hist[i];
}

__global__ __launch_bounds__(256) void radix_x1_k(R3Args a) {
  int y = blockIdx.y, blk = blockIdx.x;
  int NB = a.NB[y];
  if (blk >= NB) return;
  __shared__ int cur[MAXBIN];
  int nbin = a.nbin[y];
  const int* bhs = a.bhs[y];
  for (int i = threadIdx.x; i < nbin; i += 256) cur[i] = bhs[i * NB + blk];
  __syncthreads();
  int e0 = blk * EPB, e1 = min(e0 + EPB, a.E[y]);
  const int* dst = a.dst[y];
  const int* src = a.src[y];
  unsigned int* tmp = a.tmp[y];
  for (int e = e0 + threadIdx.x; e < e1; e += 256) {
    int d = dst[e];
    int pos = atomicAdd(&cur[d >> 8], 1);
    tmp[pos] = ((unsigned int)(d & 255) << 24) | (unsigned int)src[e];
  }
}

__global__ __launch_bounds__(256) void radix_p2_k(R3Args a) {
  int y = blockIdx.y, bin = blockIdx.x;
  if (bin >= a.nbin[y]) return;
  __shared__ int hist[256], scn[256], cursor[256];
  int t = threadIdx.x;
  hist[t] = 0;
  __syncthreads();
  const int* bhs = a.bhs[y];
  int NB = a.NB[y];
  int base = bhs[bin * NB];
  int end  = (bin + 1 < a.nbin[y]) ? bhs[(bin + 1) * NB] : a.E[y];
  const unsigned int* tmp = a.tmp[y];
  for (int i = base + t; i < end; i += 256)
    atomicAdd(&hist[tmp[i] >> 24], 1);
  __syncthreads();
  int v = hist[t];
  scn[t] = v; __syncthreads();
  int acc = v;
  for (int o = 1; o < 256; o <<= 1) {
    int u = (t >= o) ? scn[t - o] : 0;
    __syncthreads();
    acc += u; scn[t] = acc;
    __syncthreads();
  }
  int ex = acc - v;
  cursor[t] = ex;
  int d = bin * 256 + t;
  if (d < a.N[y]) { a.cnt[y][d] = v; a.rs[y][d] = base + ex; }
  __syncthreads();
  int* bkt = a.bkt[y];
  for (int i = base + t; i < end; i += 256) {
    unsigned int p = tmp[i];
    int pos = atomicAdd(&cursor[p >> 24], 1);
    bkt[base + pos] = (int)(p & 0xFFFFFFu);
  }
}

// ==== hierarchical exclusive scan (for bh -> bhs) ====
struct S3Args {
  const int* cnt[3]; int* bsum[3]; int* rs[3];
  int n[3]; int nb[3];
};

__global__ __launch_bounds__(256) void blocksum3_k(S3Args a) {
  int y = blockIdx.y;
  int n = a.n[y];
  if (blockIdx.x * 1024 >= n) return;
  __shared__ int red[256];
  int t = threadIdx.x;
  int base = blockIdx.x * 1024 + t * 4;
  int s = 0;
  #pragma unroll
  for (int i = 0; i < 4; ++i) { int idx = base + i; if (idx < n) s += a.cnt[y][idx]; }
  red[t] = s; __syncthreads();
  #pragma unroll
  for (int o = 128; o > 0; o >>= 1) { if (t < o) red[t] += red[t + o]; __syncthreads(); }
  if (t == 0) a.bsum[y][blockIdx.x] = red[0];
}

__global__ __launch_bounds__(256) void partials3_k(S3Args a) {
  __shared__ int sm[256];
  int y = blockIdx.x;
  int nb = a.nb[y];
  int t = threadIdx.x;
  int v = (t < nb) ? a.bsum[y][t] : 0;
  sm[t] = v; __syncthreads();
  int acc = v;
  for (int o = 1; o < 256; o <<= 1) {
    int u = (t >= o) ? sm[t - o] : 0;
    __syncthreads();
    acc += u; sm[t] = acc;
    __syncthreads();
  }
  if (t < nb) a.bsum[y][t] = acc - v;  // exclusive
}

__global__ __launch_bounds__(256) void scanwrite3_k(S3Args a) {
  int y = blockIdx.y;
  int n = a.n[y];
  if (blockIdx.x * 1024 >= n) return;
  __shared__ int ts[256];
  int t = threadIdx.x;
  int base = blockIdx.x * 1024 + t * 4;
  int v[4]; int s = 0;
  #pragma unroll
  for (int i = 0; i < 4; ++i) { int idx = base + i; v[i] = (idx < n) ? a.cnt[y][idx] : 0; s += v[i]; }
  ts[t] = s; __syncthreads();
  int inc = s;
  for (int o = 1; o < 256; o <<= 1) {
    int u = (t >= o) ? ts[t - o] : 0;
    __syncthreads();
    inc += u; ts[t] = inc;
    __syncthreads();
  }
  int p = a.bsum[y][blockIdx.x] + inc - s;
  #pragma unroll
  for (int i = 0; i < 4; ++i) { int idx = base + i; if (idx < n) { a.rs[y][idx] = p; p += v[i]; } }
}

// ---- weight rearrange (fp32 -> bf16 B-fragments): wf[((kc*CF+cf)*64+lane)*8+i]=W[k][c] ----
struct WArgs {
  const float* w[10];
  unsigned short* wf[10];
};
__global__ __launch_bounds__(256) void warrange_k(WArgs args) {
  int widx = blockIdx.y;
  int OUTi = (widx < 5) ? 128 : 64;
  int CF = OUTi / 16;
  int nt = 4 * CF * 64;
  int t = blockIdx.x * 256 + threadIdx.x;
  if (t >= nt) return;
  int lane = t & 63, tmp = t >> 6;
  int cf = tmp % CF, kc = tmp / CF;
  int k0 = kc * 32 + (lane >> 4) * 8;
  int c  = cf * 16 + (lane & 15);
  const float* w = args.w[widx];
  s8v v;
  #pragma unroll
  for (int i = 0; i < 8; ++i) v[i] = (short)bf16_rne(w[(k0 + i) * OUTi + c]);
  *(reinterpret_cast<s8v*>(args.wf[widx]) + t) = v;
}

// ==== fused gather-max + GEMM layer kernel ====
// Phase 1: gather segmax of relation sources into swizzled LDS tiles.
// Phase 2: out = relu?(root@Wroot + b + lds1@Wrel1 [+ lds2@Wrel2]).
// LDS swizzle: byte = row*256 + col16  XOR  (row&7)<<4 (both write & read).
// MFMA 16x16x32 bf16: A row=lane&15,k=(lane>>4)*8+i; B col=lane&15;
//                     D col=lane&15,row=(lane>>4)*4+reg.

__device__ __forceinline__ void gather_to_lds(
    unsigned short* __restrict__ ldsT,
    const int* __restrict__ cnt, const int* __restrict__ rs,
    const int* __restrict__ bkt, const unsigned short* __restrict__ X,
    int row0, int N)
{
  const int t = threadIdx.x;
  const int lg = t & 15;        // feature slice (8 bf16 = 16B)
  const int rr = t >> 4;        // 0..15
  #pragma unroll
  for (int pass = 0; pass < 4; ++pass) {
    const int r = pass * 16 + rr;      // block-local row 0..63
    const int d = row0 + r;
    uint4 o; o.x = o.y = o.z = o.w = 0u;
    if (d < N) {
      const int deg = cnt[d];
      if (deg > 0) {
        const int* bp = bkt + rs[d];
        float ml[4], mh[4];
        #pragma unroll
        for (int j = 0; j < 4; ++j) { ml[j] = -3.4e38f; mh[j] = -3.4e38f; }
        int s0 = bp[0];
        for (int e = 0; e < deg; e += 2) {
          int s1 = (e + 1 < deg) ? bp[e + 1] : s0;   // branchless tail
          int sn = (e + 2 < deg) ? bp[e + 2] : s0;
          uint4 r0 = *reinterpret_cast<const uint4*>(X + (size_t)s0 * DI + lg * 8);
          uint4 r1 = *reinterpret_cast<const uint4*>(X + (size_t)s1 * DI + lg * 8);
          unsigned int w0[4] = {r0.x, r0.y, r0.z, r0.w};
          unsigned int w1[4] = {r1.x, r1.y, r1.z, r1.w};
          #pragma unroll
          for (int j = 0; j < 4; ++j) {
            ml[j] = fmaxf(ml[j], __uint_as_float(w0[j] << 16));
            mh[j] = fmaxf(mh[j], __uint_as_float(w0[j] & 0xFFFF0000u));
            ml[j] = fmaxf(ml[j], __uint_as_float(w1[j] << 16));
            mh[j] = fmaxf(mh[j], __uint_as_float(w1[j] & 0xFFFF0000u));
          }
          s0 = sn;
        }
        o.x = (__float_as_uint(ml[0]) >> 16) | (__float_as_uint(mh[0]) & 0xFFFF0000u);
        o.y = (__float_as_uint(ml[1]) >> 16) | (__float_as_uint(mh[1]) & 0xFFFF0000u);
        o.z = (__float_as_uint(ml[2]) >> 16) | (__float_as_uint(mh[2]) & 0xFFFF0000u);
        o.w = (__float_as_uint(ml[3]) >> 16) | (__float_as_uint(mh[3]) & 0xFFFF0000u);
      }
    }
    const int byte = (r * 256 + lg * 16) ^ ((r & 7) << 4);
    *reinterpret_cast<uint4*>(reinterpret_cast<char*>(ldsT) + byte) = o;
  }
}

template<int CF>
__device__ __forceinline__ void mfma_global(const unsigned short* __restrict__ A,
                                            const unsigned short* __restrict__ W,
                                            f32x4* acc, size_t arow, int lane, int half) {
  const s8v* a = reinterpret_cast<const s8v*>(A + arow * DI + half * 8);
  const s8v* w = reinterpret_cast<const s8v*>(W) + lane;
  #pragma unroll
  for (int kc = 0; kc < 4; ++kc) {
    s8v av = a[kc * 4];
    #pragma unroll
    for (int cf = 0; cf < CF; ++cf)
      acc[cf] = __builtin_amdgcn_mfma_f32_16x16x32_bf16(av, w[(kc * CF + cf) * 64], acc[cf], 0, 0, 0);
  }
}

template<int CF>
__device__ __forceinline__ void mfma_lds(const unsigned short* __restrict__ ldsT,
                                         const unsigned short* __restrict__ W,
                                         f32x4* acc, int wrow, int lane) {
  const int rl = lane & 15, half = lane >> 4;
  const int r = wrow + rl;  // block-local row
  const s8v* w = reinterpret_cast<const s8v*>(W) + lane;
  #pragma unroll
  for (int kc = 0; kc < 4; ++kc) {
    const int byte = (r * 256 + half * 16 + kc * 64) ^ ((r & 7) << 4);
    s8v av = *reinterpret_cast<const s8v*>(reinterpret_cast<const char*>(ldsT) + byte);
    #pragma unroll
    for (int cf = 0; cf < CF; ++cf)
      acc[cf] = __builtin_amdgcn_mfma_f32_16x16x32_bf16(av, w[(kc * CF + cf) * 64], acc[cf], 0, 0, 0);
  }
}

struct FLArgs {
  const unsigned short *root[2], *Wroot[2];
  const unsigned short *feat1[2], *Wrel1[2];
  const unsigned short *feat2,    *Wrel2;       // paper-only second relation
  const int *cnt1[2], *rs1[2], *bkt1[2];
  const int *cnt2,    *rs2,    *bkt2;
  const float* bias[2];
  void* out[2];
  int N[2];
  int blocks0;
};

template<int OUT, bool RELU, bool OUT_BF16>
__global__ __launch_bounds__(256) void fused_layer_k(FLArgs g) {
  constexpr int CF = OUT / 16;
  __shared__ unsigned short lds1[64 * 128];
  __shared__ unsigned short lds2[64 * 128];

  const int p = (blockIdx.x >= (unsigned)g.blocks0) ? 1 : 0;
  const int brow = blockIdx.x - (p ? g.blocks0 : 0);
  const int N = g.N[p];
  const int row0 = brow * 64;
  if (row0 >= N) return;

  // phase 1: gather segmax into LDS (swizzled)
  gather_to_lds(lds1, g.cnt1[p], g.rs1[p], g.bkt1[p], g.feat1[p], row0, N);
  if (p == 0)
    gather_to_lds(lds2, g.cnt2, g.rs2, g.bkt2, g.feat2, row0, N);
  __syncthreads();

  // phase 2: MFMA GEMM
  const int lane = threadIdx.x & 63;
  const int wave = threadIdx.x >> 6;
  const int wrow = wave * 16;             // block-local
  const int rl = lane & 15, half = lane >> 4;
  const size_t arow = (size_t)(row0 + wrow + rl);

  f32x4 acc[CF];
  #pragma unroll
  for (int i = 0; i < CF; ++i) acc[i] = f32x4{0.f, 0.f, 0.f, 0.f};

  mfma_global<CF>(g.root[p], g.Wroot[p], acc, arow, lane, half);
  mfma_lds<CF>(lds1, g.Wrel1[p], acc, wrow, lane);
  if (p == 0) mfma_lds<CF>(lds2, g.Wrel2, acc, wrow, lane);

  const float* bias = g.bias[p];
  #pragma unroll
  for (int cf = 0; cf < CF; ++cf) {
    float bv = bias[cf * 16 + rl];
    #pragma unroll
    for (int j = 0; j < 4; ++j) {
      int r = row0 + wrow + half * 4 + j;
      if (r >= N) continue;
      float v = acc[cf][j] + bv;
      if (RELU) v = v > 0.f ? v : 0.f;
      size_t idx = (size_t)r * OUT + cf * 16 + rl;
      if (OUT_BF16) ((unsigned short*)g.out[p])[idx] = bf16_rne(v);
      else          ((float*)g.out[p])[idx] = v;
    }
  }
}

extern "C" void kernel_launch(void* const* d_in, const int* in_sizes, int n_in,
                              void* d_out, int out_size, void* d_ws, size_t ws_size,
                              hipStream_t stream) {
  const float* xp = (const float*)d_in[0];
  const float* xa = (const float*)d_in[1];
  const int* wsrc = (const int*)d_in[2];
  const int* wdst = (const int*)d_in[3];
  const int* csrc = (const int*)d_in[4];
  const int* cdst = (const int*)d_in[5];
  const int* bsrc = (const int*)d_in[6];
  const int* bdst = (const int*)d_in[7];
  const int Ew = in_sizes[2], Ec = in_sizes[4], Eb = in_sizes[6];

  const float* w1w  = (const float*)d_in[8];
  const float* w1c  = (const float*)d_in[9];
  const float* w1wb = (const float*)d_in[10];
  const float* w1rp = (const float*)d_in[11];
  const float* b1rp = (const float*)d_in[12];
  const float* w1ra = (const float*)d_in[13];
  const float* b1ra = (const float*)d_in[14];
  const float* w2w  = (const float*)d_in[15];
  const float* w2c  = (const float*)d_in[16];
  const float* w2wb = (const float*)d_in[17];
  const float* w2rp = (const float*)d_in[18];
  const float* b2rp = (const float*)d_in[19];
  const float* w2ra = (const float*)d_in[20];
  const float* b2ra = (const float*)d_in[21];

  // ---- workspace layout (bytes) ----
  char* ws = (char*)d_ws;
  unsigned short* xpb = (unsigned short*)(ws + 0);           // 25,600,000
  unsigned short* xab = (unsigned short*)(ws + 25600000);    // 12,800,000
  unsigned short* hp  = (unsigned short*)(ws + 38400000);    // 25,600,000
  unsigned short* ha  = (unsigned short*)(ws + 64000000);    // 12,800,000
  // S_* buffers eliminated (R7); region 76.8M..140.8M reused for bh/bhs only.
  int* bkt_w = (int*)(ws + 140800000);                       // 3,200,000
  int* bkt_c = (int*)(ws + 144000000);                       // 3,200,000
  int* bkt_b = (int*)(ws + 147200000);                       // 3,200,000
  int* cnt_w = (int*)(ws + 150400000);                       // 400,000
  int* cnt_c = (int*)(ws + 150800000);                       // 400,000
  int* cnt_b = (int*)(ws + 151200000);                       // 200,000
  int* rs_w  = (int*)(ws + 151400000);                       // 400,000
  int* rs_c  = (int*)(ws + 151800000);                       // 400,000
  int* rs_b  = (int*)(ws + 152200000);                       // 200,000
  int* bsum_w = (int*)(ws + 152400000);                      // 4,096
  int* bsum_c = (int*)(ws + 152404096);                      // 4,096
  int* bsum_b = (int*)(ws + 152408192);                      // 4,096
  unsigned short* wf = (unsigned short*)(ws + 152412288);    // 245,760
  unsigned int* tmp_w = (unsigned int*)(ws + 152660000);     // 3,200,000
  unsigned int* tmp_c = (unsigned int*)(ws + 155860000);     // 3,200,000
  unsigned int* tmp_b = (unsigned int*)(ws + 159060000);     // 3,200,000
  int* bh_w  = (int*)(ws + 76800000);                        // 306,544
  int* bh_c  = (int*)(ws + 77110000);                        // 306,544
  int* bh_b  = (int*)(ws + 77420000);                        // 153,664
  int* bhs_w = (int*)(ws + 77580000);                        // 306,544
  int* bhs_c = (int*)(ws + 77890000);                        // 306,544
  int* bhs_b = (int*)(ws + 78200000);                        // 153,664

  unsigned short* WF[10];
  size_t off = 0;
  for (int i = 0; i < 10; ++i) {
    WF[i] = wf + off;
    off += (i < 5) ? (size_t)128 * 128 : (size_t)128 * 64;
  }
  WArgs wa;
  const float* wsrcs[10] = {w1w, w1c, w1wb, w1rp, w1ra, w2w, w2c, w2wb, w2rp, w2ra};
  for (int i = 0; i < 10; ++i) { wa.w[i] = wsrcs[i]; wa.wf[i] = WF[i]; }

  float* outP = (float*)d_out;              // 100000 x 64 fp32
  float* outA = outP + (size_t)NP * 64;     // 50000 x 64 fp32

  const int gP = (NP + 63) / 64, gA = (NA + 63) / 64;  // 1563, 782

  // ---- radix CSR args ----
  R3Args ra;
  ra.src[0] = wsrc; ra.dst[0] = wdst; ra.E[0] = Ew; ra.N[0] = NP;
  ra.src[1] = csrc; ra.dst[1] = cdst; ra.E[1] = Ec; ra.N[1] = NP;
  ra.src[2] = bsrc; ra.dst[2] = bdst; ra.E[2] = Eb; ra.N[2] = NA;
  ra.bh[0] = bh_w; ra.bh[1] = bh_c; ra.bh[2] = bh_b;
  ra.bhs[0] = bhs_w; ra.bhs[1] = bhs_c; ra.bhs[2] = bhs_b;
  ra.tmp[0] = tmp_w; ra.tmp[1] = tmp_c; ra.tmp[2] = tmp_b;
  ra.bkt[0] = bkt_w; ra.bkt[1] = bkt_c; ra.bkt[2] = bkt_b;
  ra.cnt[0] = cnt_w; ra.cnt[1] = cnt_c; ra.cnt[2] = cnt_b;
  ra.rs[0] = rs_w; ra.rs[1] = rs_c; ra.rs[2] = rs_b;
  int gSX = 0, gSC = 0, maxbin = 0;
  for (int y = 0; y < 3; ++y) {
    ra.nbin[y] = (ra.N[y] + 255) >> 8;
    ra.NB[y] = (ra.E[y] + EPB - 1) / EPB;
    if (ra.NB[y] > gSX) gSX = ra.NB[y];
    if (ra.nbin[y] > maxbin) maxbin = ra.nbin[y];
  }
  S3Args sa;
  sa.bsum[0] = bsum_w; sa.bsum[1] = bsum_c; sa.bsum[2] = bsum_b;
  for (int y = 0; y < 3; ++y) {
    sa.cnt[y] = ra.bh[y]; sa.rs[y] = ra.bhs[y];
    sa.n[y] = ra.nbin[y] * ra.NB[y];
    sa.nb[y] = (sa.n[y] + 1023) / 1024;
    if (sa.nb[y] > gSC) gSC = sa.nb[y];
  }

  // ---- fused layer args ----
  FLArgs f1, f2;
  // layer 1: paper = xpb@WF3 + segmax_w(xab)@WF0 + segmax_c(xpb)@WF1 + b1rp -> hp
  //          author = xab@WF4 + segmax_b(xpb)@WF2 + b1ra -> ha
  f1.root[0] = xpb; f1.Wroot[0] = WF[3];
  f1.feat1[0] = xab; f1.Wrel1[0] = WF[0];
  f1.cnt1[0] = cnt_w; f1.rs1[0] = rs_w; f1.bkt1[0] = bkt_w;
  f1.feat2 = xpb; f1.Wrel2 = WF[1];
  f1.cnt2 = cnt_c; f1.rs2 = rs_c; f1.bkt2 = bkt_c;
  f1.bias[0] = b1rp; f1.out[0] = hp; f1.N[0] = NP;
  f1.root[1] = xab; f1.Wroot[1] = WF[4];
  f1.feat1[1] = xpb; f1.Wrel1[1] = WF[2];
  f1.cnt1[1] = cnt_b; f1.rs1[1] = rs_b; f1.bkt1[1] = bkt_b;
  f1.bias[1] = b1ra; f1.out[1] = ha; f1.N[1] = NA;
  f1.blocks0 = gP;
  // layer 2: paper = hp@WF8 + segmax_w(ha)@WF5 + segmax_c(hp)@WF6 + b2rp -> outP
  //          author = ha@WF9 + segmax_b(hp)@WF7 + b2ra -> outA
  f2.root[0] = hp; f2.Wroot[0] = WF[8];
  f2.feat1[0] = ha; f2.Wrel1[0] = WF[5];
  f2.cnt1[0] = cnt_w; f2.rs1[0] = rs_w; f2.bkt1[0] = bkt_w;
  f2.feat2 = hp; f2.Wrel2 = WF[6];
  f2.cnt2 = cnt_c; f2.rs2 = rs_c; f2.bkt2 = bkt_c;
  f2.bias[0] = b2rp; f2.out[0] = outP; f2.N[0] = NP;
  f2.root[1] = ha; f2.Wroot[1] = WF[9];
  f2.feat1[1] = hp; f2.Wrel1[1] = WF[7];
  f2.cnt1[1] = cnt_b; f2.rs1[1] = rs_b; f2.bkt1[1] = bkt_b;
  f2.bias[1] = b2ra; f2.out[1] = outA; f2.N[1] = NA;
  f2.blocks0 = gP;

  const int n4p = NP * DI / 4, n4a = NA * DI / 4;

  // ---- prep ----
  warrange_k<<<dim3(8, 10), 256, 0, stream>>>(wa);
  cvt2_k<<<(n4p + n4a + 255) / 256, 256, 0, stream>>>(xp, xpb, n4p, xa, xab, n4a);

  // ---- CSR build (no global atomics, no memsets) ----
  radix_s1_k<<<dim3(gSX, 3), 256, 0, stream>>>(ra);
  blocksum3_k<<<dim3(gSC, 3), 256, 0, stream>>>(sa);
  partials3_k<<<3, 256, 0, stream>>>(sa);
  scanwrite3_k<<<dim3(gSC, 3), 256, 0, stream>>>(sa);
  radix_x1_k<<<dim3(gSX, 3), 256, 0, stream>>>(ra);
  radix_p2_k<<<dim3(maxbin, 3), 256, 0, stream>>>(ra);

  // ---- fused layers ----
  fused_layer_k<128, true, true><<<gP + gA, 256, 0, stream>>>(f1);
  fused_layer_k<64, false, false><<<gP + gA, 256, 0, stream>>>(f2);
}

// Round 8
// 367.695 us; speedup vs baseline: 1.0694x; 1.0694x over previous
//
#include <hip/hip_runtime.h>

// RGCN 2-layer hetero graph conv. fp32 I/O, bf16 MFMA compute.
// R8: register-resident gather fused into the GEMM — no LDS, no barrier.
// Each lane privately segmax-gathers its OWN MFMA A-fragment slice
// (row=lane&15, k-slice=(lane>>4)*8 + kc*32) into 32 running-max VGPRs,
// repacks to bf16 (exact), and MFMAs directly. Kills R7's __syncthreads
// straggler coupling and the 32KB LDS occupancy cap while keeping the
// fusion's traffic win (no S buffers). CSR build: R6 radix sort (unchanged).

#define DI 128
#define NP 100000
#define NA 50000
#define EPB 4096
#define MAXBIN 391

typedef short s8v __attribute__((ext_vector_type(8)));
typedef float f32x4 __attribute__((ext_vector_type(4)));
typedef unsigned int u32x4 __attribute__((ext_vector_type(4)));

__device__ __forceinline__ unsigned short bf16_rne(float f) {
  unsigned int fb = __float_as_uint(f);
  fb += 0x7FFFu + ((fb >> 16) & 1u);
  return (unsigned short)(fb >> 16);
}

// ---- fp32 -> bf16, both tables in one dispatch ----
__global__ __launch_bounds__(256) void cvt2_k(const float* __restrict__ Xp,
                                              unsigned short* __restrict__ Yp, int n4p,
                                              const float* __restrict__ Xa,
                                              unsigned short* __restrict__ Ya, int n4a) {
  int i = blockIdx.x * 256 + threadIdx.x;
  const float* X; unsigned short* Y;
  if (i < n4p) { X = Xp; Y = Yp; }
  else { i -= n4p; if (i >= n4a) return; X = Xa; Y = Ya; }
  float4 f = reinterpret_cast<const float4*>(X)[i];
  ushort4 o;
  o.x = bf16_rne(f.x); o.y = bf16_rne(f.y); o.z = bf16_rne(f.z); o.w = bf16_rne(f.w);
  reinterpret_cast<ushort4*>(Y)[i] = o;
}

// ==== radix CSR build (3 edge types via blockIdx.y) ====
struct R3Args {
  const int* src[3]; const int* dst[3];
  int* bh[3]; int* bhs[3];
  unsigned int* tmp[3];
  int* bkt[3]; int* cnt[3]; int* rs[3];
  int E[3]; int N[3]; int nbin[3]; int NB[3];
};

__global__ __launch_bounds__(256) void radix_s1_k(R3Args a) {
  int y = blockIdx.y, blk = blockIdx.x;
  int NB = a.NB[y];
  if (blk >= NB) return;
  __shared__ int hist[MAXBIN];
  int nbin = a.nbin[y];
  for (int i = threadIdx.x; i < nbin; i += 256) hist[i] = 0;
  __syncthreads();
  int e0 = blk * EPB, e1 = min(e0 + EPB, a.E[y]);
  const int* dst = a.dst[y];
  for (int e = e0 + threadIdx.x; e < e1; e += 256)
    atomicAdd(&hist[dst[e] >> 8], 1);
  __syncthreads();
  int* bh = a.bh[y];
  for (int i = threadIdx.x; i < nbin; i += 256) bh[i * NB + blk] = hist[i];
}

__global__ __launch_bounds__(256) void radix_x1_k(R3Args a) {
  int y = blockIdx.y, blk = blockIdx.x;
  int NB = a.NB[y];
  if (blk >= NB) return;
  __shared__ int cur[MAXBIN];
  int nbin = a.nbin[y];
  const int* bhs = a.bhs[y];
  for (int i = threadIdx.x; i < nbin; i += 256) cur[i] = bhs[i * NB + blk];
  __syncthreads();
  int e0 = blk * EPB, e1 = min(e0 + EPB, a.E[y]);
  const int* dst = a.dst[y];
  const int* src = a.src[y];
  unsigned int* tmp = a.tmp[y];
  for (int e = e0 + threadIdx.x; e < e1; e += 256) {
    int d = dst[e];
    int pos = atomicAdd(&cur[d >> 8], 1);
    tmp[pos] = ((unsigned int)(d & 255) << 24) | (unsigned int)src[e];
  }
}

__global__ __launch_bounds__(256) void radix_p2_k(R3Args a) {
  int y = blockIdx.y, bin = blockIdx.x;
  if (bin >= a.nbin[y]) return;
  __shared__ int hist[256], scn[256], cursor[256];
  int t = threadIdx.x;
  hist[t] = 0;
  __syncthreads();
  const int* bhs = a.bhs[y];
  int NB = a.NB[y];
  int base = bhs[bin * NB];
  int end  = (bin + 1 < a.nbin[y]) ? bhs[(bin + 1) * NB] : a.E[y];
  const unsigned int* tmp = a.tmp[y];
  for (int i = base + t; i < end; i += 256)
    atomicAdd(&hist[tmp[i] >> 24], 1);
  __syncthreads();
  int v = hist[t];
  scn[t] = v; __syncthreads();
  int acc = v;
  for (int o = 1; o < 256; o <<= 1) {
    int u = (t >= o) ? scn[t - o] : 0;
    __syncthreads();
    acc += u; scn[t] = acc;
    __syncthreads();
  }
  int ex = acc - v;
  cursor[t] = ex;
  int d = bin * 256 + t;
  if (d < a.N[y]) { a.cnt[y][d] = v; a.rs[y][d] = base + ex; }
  __syncthreads();
  int* bkt = a.bkt[y];
  for (int i = base + t; i < end; i += 256) {
    unsigned int p = tmp[i];
    int pos = atomicAdd(&cursor[p >> 24], 1);
    bkt[base + pos] = (int)(p & 0xFFFFFFu);
  }
}

// ==== hierarchical exclusive scan (for bh -> bhs) ====
struct S3Args {
  const int* cnt[3]; int* bsum[3]; int* rs[3];
  int n[3]; int nb[3];
};

__global__ __launch_bounds__(256) void blocksum3_k(S3Args a) {
  int y = blockIdx.y;
  int n = a.n[y];
  if (blockIdx.x * 1024 >= n) return;
  __shared__ int red[256];
  int t = threadIdx.x;
  int base = blockIdx.x * 1024 + t * 4;
  int s = 0;
  #pragma unroll
  for (int i = 0; i < 4; ++i) { int idx = base + i; if (idx < n) s += a.cnt[y][idx]; }
  red[t] = s; __syncthreads();
  #pragma unroll
  for (int o = 128; o > 0; o >>= 1) { if (t < o) red[t] += red[t + o]; __syncthreads(); }
  if (t == 0) a.bsum[y][blockIdx.x] = red[0];
}

__global__ __launch_bounds__(256) void partials3_k(S3Args a) {
  __shared__ int sm[256];
  int y = blockIdx.x;
  int nb = a.nb[y];
  int t = threadIdx.x;
  int v = (t < nb) ? a.bsum[y][t] : 0;
  sm[t] = v; __syncthreads();
  int acc = v;
  for (int o = 1; o < 256; o <<= 1) {
    int u = (t >= o) ? sm[t - o] : 0;
    __syncthreads();
    acc += u; sm[t] = acc;
    __syncthreads();
  }
  if (t < nb) a.bsum[y][t] = acc - v;  // exclusive
}

__global__ __launch_bounds__(256) void scanwrite3_k(S3Args a) {
  int y = blockIdx.y;
  int n = a.n[y];
  if (blockIdx.x * 1024 >= n) return;
  __shared__ int ts[256];
  int t = threadIdx.x;
  int base = blockIdx.x * 1024 + t * 4;
  int v[4]; int s = 0;
  #pragma unroll
  for (int i = 0; i < 4; ++i) { int idx = base + i; v[i] = (idx < n) ? a.cnt[y][idx] : 0; s += v[i]; }
  ts[t] = s; __syncthreads();
  int inc = s;
  for (int o = 1; o < 256; o <<= 1) {
    int u = (t >= o) ? ts[t - o] : 0;
    __syncthreads();
    inc += u; ts[t] = inc;
    __syncthreads();
  }
  int p = a.bsum[y][blockIdx.x] + inc - s;
  #pragma unroll
  for (int i = 0; i < 4; ++i) { int idx = base + i; if (idx < n) { a.rs[y][idx] = p; p += v[i]; } }
}

// ---- weight rearrange (fp32 -> bf16 B-fragments): wf[((kc*CF+cf)*64+lane)*8+i]=W[k][c] ----
struct WArgs {
  const float* w[10];
  unsigned short* wf[10];
};
__global__ __launch_bounds__(256) void warrange_k(WArgs args) {
  int widx = blockIdx.y;
  int OUTi = (widx < 5) ? 128 : 64;
  int CF = OUTi / 16;
  int nt = 4 * CF * 64;
  int t = blockIdx.x * 256 + threadIdx.x;
  if (t >= nt) return;
  int lane = t & 63, tmp = t >> 6;
  int cf = tmp % CF, kc = tmp / CF;
  int k0 = kc * 32 + (lane >> 4) * 8;
  int c  = cf * 16 + (lane & 15);
  const float* w = args.w[widx];
  s8v v;
  #pragma unroll
  for (int i = 0; i < 8; ++i) v[i] = (short)bf16_rne(w[(k0 + i) * OUTi + c]);
  *(reinterpret_cast<s8v*>(args.wf[widx]) + t) = v;
}

// ==== fused layer: register-gather segmax + MFMA GEMM, no LDS, no barrier ====
// MFMA 16x16x32 bf16: A row=lane&15,k=(lane>>4)*8+i; B col=lane&15;
//                     D col=lane&15,row=(lane>>4)*4+reg.

template<int CF>
__device__ __forceinline__ void mfma_global(const unsigned short* __restrict__ A,
                                            const unsigned short* __restrict__ W,
                                            f32x4* acc, size_t arow, int lane, int half) {
  const s8v* a = reinterpret_cast<const s8v*>(A + arow * DI + half * 8);
  const s8v* w = reinterpret_cast<const s8v*>(W) + lane;
  #pragma unroll
  for (int kc = 0; kc < 4; ++kc) {
    s8v av = a[kc * 4];
    #pragma unroll
    for (int cf = 0; cf < CF; ++cf)
      acc[cf] = __builtin_amdgcn_mfma_f32_16x16x32_bf16(av, w[(kc * CF + cf) * 64], acc[cf], 0, 0, 0);
  }
}

// Each lane gathers its own A-fragment slice: row d (=lane&15 within wave-tile),
// k-slice half*8 + kc*32, kc=0..3. 32 running-max floats in VGPRs.
template<int CF>
__device__ __forceinline__ void gather_mfma(
    const int* __restrict__ cnt, const int* __restrict__ rs,
    const int* __restrict__ bkt, const unsigned short* __restrict__ X,
    const unsigned short* __restrict__ W,
    f32x4* acc, int d, int N, int half, int lane)
{
  float ml[4][4], mh[4][4];
  int deg = 0, base = 0;
  if (d < N) { deg = cnt[d]; base = rs[d]; }
  if (deg > 0) {
    #pragma unroll
    for (int kc = 0; kc < 4; ++kc)
      #pragma unroll
      for (int j = 0; j < 4; ++j) { ml[kc][j] = -3.4e38f; mh[kc][j] = -3.4e38f; }
    const int* bp = bkt + base;
    int s0 = bp[0];
    for (int e = 0; e < deg; e += 2) {
      int s1 = (e + 1 < deg) ? bp[e + 1] : s0;   // branchless tail: re-max same row
      int sn = (e + 2 < deg) ? bp[e + 2] : s0;
      const unsigned short* x0 = X + (size_t)s0 * DI + half * 8;
      const unsigned short* x1 = X + (size_t)s1 * DI + half * 8;
      #pragma unroll
      for (int kc = 0; kc < 4; ++kc) {
        uint4 r0 = *reinterpret_cast<const uint4*>(x0 + kc * 32);
        uint4 r1 = *reinterpret_cast<const uint4*>(x1 + kc * 32);
        unsigned int w0[4] = {r0.x, r0.y, r0.z, r0.w};
        unsigned int w1[4] = {r1.x, r1.y, r1.z, r1.w};
        #pragma unroll
        for (int j = 0; j < 4; ++j) {
          ml[kc][j] = fmaxf(ml[kc][j], __uint_as_float(w0[j] << 16));
          mh[kc][j] = fmaxf(mh[kc][j], __uint_as_float(w0[j] & 0xFFFF0000u));
          ml[kc][j] = fmaxf(ml[kc][j], __uint_as_float(w1[j] << 16));
          mh[kc][j] = fmaxf(mh[kc][j], __uint_as_float(w1[j] & 0xFFFF0000u));
        }
      }
      s0 = sn;
    }
  } else {
    #pragma unroll
    for (int kc = 0; kc < 4; ++kc)
      #pragma unroll
      for (int j = 0; j < 4; ++j) { ml[kc][j] = 0.f; mh[kc][j] = 0.f; }
  }
  const s8v* w = reinterpret_cast<const s8v*>(W) + lane;
  #pragma unroll
  for (int kc = 0; kc < 4; ++kc) {
    u32x4 t;
    #pragma unroll
    for (int j = 0; j < 4; ++j)
      t[j] = (__float_as_uint(mh[kc][j]) & 0xFFFF0000u) | (__float_as_uint(ml[kc][j]) >> 16);
    s8v av = __builtin_bit_cast(s8v, t);
    #pragma unroll
    for (int cf = 0; cf < CF; ++cf)
      acc[cf] = __builtin_amdgcn_mfma_f32_16x16x32_bf16(av, w[(kc * CF + cf) * 64], acc[cf], 0, 0, 0);
  }
}

struct FLArgs {
  const unsigned short *root[2], *Wroot[2];
  const unsigned short *feat1[2], *Wrel1[2];
  const unsigned short *feat2,    *Wrel2;       // paper-only second relation
  const int *cnt1[2], *rs1[2], *bkt1[2];
  const int *cnt2,    *rs2,    *bkt2;
  const float* bias[2];
  void* out[2];
  int N[2];
  int blocks0;
};

template<int OUT, bool RELU, bool OUT_BF16>
__global__ __launch_bounds__(256) void fused_layer_k(FLArgs g) {
  constexpr int CF = OUT / 16;
  const int p = (blockIdx.x >= (unsigned)g.blocks0) ? 1 : 0;
  const int brow = blockIdx.x - (p ? g.blocks0 : 0);
  const int N = g.N[p];
  const int lane = threadIdx.x & 63;
  const int wave = threadIdx.x >> 6;
  const int rl = lane & 15, half = lane >> 4;
  const int row0 = brow * 64 + wave * 16;
  if (row0 >= N) return;
  const int d = row0 + rl;                       // this lane's A/gather row
  const size_t arow = (size_t)((d < N) ? d : (N - 1));

  f32x4 acc[CF];
  #pragma unroll
  for (int i = 0; i < CF; ++i) acc[i] = f32x4{0.f, 0.f, 0.f, 0.f};

  mfma_global<CF>(g.root[p], g.Wroot[p], acc, arow, lane, half);
  gather_mfma<CF>(g.cnt1[p], g.rs1[p], g.bkt1[p], g.feat1[p], g.Wrel1[p],
                  acc, d, N, half, lane);
  if (p == 0)
    gather_mfma<CF>(g.cnt2, g.rs2, g.bkt2, g.feat2, g.Wrel2,
                    acc, d, N, half, lane);

  const float* bias = g.bias[p];
  #pragma unroll
  for (int cf = 0; cf < CF; ++cf) {
    float bv = bias[cf * 16 + rl];
    #pragma unroll
    for (int j = 0; j < 4; ++j) {
      int r = row0 + half * 4 + j;
      if (r >= N) continue;
      float v = acc[cf][j] + bv;
      if (RELU) v = v > 0.f ? v : 0.f;
      size_t idx = (size_t)r * OUT + cf * 16 + rl;
      if (OUT_BF16) ((unsigned short*)g.out[p])[idx] = bf16_rne(v);
      else          ((float*)g.out[p])[idx] = v;
    }
  }
}

extern "C" void kernel_launch(void* const* d_in, const int* in_sizes, int n_in,
                              void* d_out, int out_size, void* d_ws, size_t ws_size,
                              hipStream_t stream) {
  const float* xp = (const float*)d_in[0];
  const float* xa = (const float*)d_in[1];
  const int* wsrc = (const int*)d_in[2];
  const int* wdst = (const int*)d_in[3];
  const int* csrc = (const int*)d_in[4];
  const int* cdst = (const int*)d_in[5];
  const int* bsrc = (const int*)d_in[6];
  const int* bdst = (const int*)d_in[7];
  const int Ew = in_sizes[2], Ec = in_sizes[4], Eb = in_sizes[6];

  const float* w1w  = (const float*)d_in[8];
  const float* w1c  = (const float*)d_in[9];
  const float* w1wb = (const float*)d_in[10];
  const float* w1rp = (const float*)d_in[11];
  const float* b1rp = (const float*)d_in[12];
  const float* w1ra = (const float*)d_in[13];
  const float* b1ra = (const float*)d_in[14];
  const float* w2w  = (const float*)d_in[15];
  const float* w2c  = (const float*)d_in[16];
  const float* w2wb = (const float*)d_in[17];
  const float* w2rp = (const float*)d_in[18];
  const float* b2rp = (const float*)d_in[19];
  const float* w2ra = (const float*)d_in[20];
  const float* b2ra = (const float*)d_in[21];

  // ---- workspace layout (bytes) ----
  char* ws = (char*)d_ws;
  unsigned short* xpb = (unsigned short*)(ws + 0);           // 25,600,000
  unsigned short* xab = (unsigned short*)(ws + 25600000);    // 12,800,000
  unsigned short* hp  = (unsigned short*)(ws + 38400000);    // 25,600,000
  unsigned short* ha  = (unsigned short*)(ws + 64000000);    // 12,800,000
  int* bkt_w = (int*)(ws + 140800000);                       // 3,200,000
  int* bkt_c = (int*)(ws + 144000000);                       // 3,200,000
  int* bkt_b = (int*)(ws + 147200000);                       // 3,200,000
  int* cnt_w = (int*)(ws + 150400000);                       // 400,000
  int* cnt_c = (int*)(ws + 150800000);                       // 400,000
  int* cnt_b = (int*)(ws + 151200000);                       // 200,000
  int* rs_w  = (int*)(ws + 151400000);                       // 400,000
  int* rs_c  = (int*)(ws + 151800000);                       // 400,000
  int* rs_b  = (int*)(ws + 152200000);                       // 200,000
  int* bsum_w = (int*)(ws + 152400000);                      // 4,096
  int* bsum_c = (int*)(ws + 152404096);                      // 4,096
  int* bsum_b = (int*)(ws + 152408192);                      // 4,096
  unsigned short* wf = (unsigned short*)(ws + 152412288);    // 245,760
  unsigned int* tmp_w = (unsigned int*)(ws + 152660000);     // 3,200,000
  unsigned int* tmp_c = (unsigned int*)(ws + 155860000);     // 3,200,000
  unsigned int* tmp_b = (unsigned int*)(ws + 159060000);     // 3,200,000
  int* bh_w  = (int*)(ws + 76800000);                        // 306,544
  int* bh_c  = (int*)(ws + 77110000);                        // 306,544
  int* bh_b  = (int*)(ws + 77420000);                        // 153,664
  int* bhs_w = (int*)(ws + 77580000);                        // 306,544
  int* bhs_c = (int*)(ws + 77890000);                        // 306,544
  int* bhs_b = (int*)(ws + 78200000);                        // 153,664

  unsigned short* WF[10];
  size_t off = 0;
  for (int i = 0; i < 10; ++i) {
    WF[i] = wf + off;
    off += (i < 5) ? (size_t)128 * 128 : (size_t)128 * 64;
  }
  WArgs wa;
  const float* wsrcs[10] = {w1w, w1c, w1wb, w1rp, w1ra, w2w, w2c, w2wb, w2rp, w2ra};
  for (int i = 0; i < 10; ++i) { wa.w[i] = wsrcs[i]; wa.wf[i] = WF[i]; }

  float* outP = (float*)d_out;              // 100000 x 64 fp32
  float* outA = outP + (size_t)NP * 64;     // 50000 x 64 fp32

  const int gP = (NP + 63) / 64, gA = (NA + 63) / 64;  // 1563, 782

  // ---- radix CSR args ----
  R3Args ra;
  ra.src[0] = wsrc; ra.dst[0] = wdst; ra.E[0] = Ew; ra.N[0] = NP;
  ra.src[1] = csrc; ra.dst[1] = cdst; ra.E[1] = Ec; ra.N[1] = NP;
  ra.src[2] = bsrc; ra.dst[2] = bdst; ra.E[2] = Eb; ra.N[2] = NA;
  ra.bh[0] = bh_w; ra.bh[1] = bh_c; ra.bh[2] = bh_b;
  ra.bhs[0] = bhs_w; ra.bhs[1] = bhs_c; ra.bhs[2] = bhs_b;
  ra.tmp[0] = tmp_w; ra.tmp[1] = tmp_c; ra.tmp[2] = tmp_b;
  ra.bkt[0] = bkt_w; ra.bkt[1] = bkt_c; ra.bkt[2] = bkt_b;
  ra.cnt[0] = cnt_w; ra.cnt[1] = cnt_c; ra.cnt[2] = cnt_b;
  ra.rs[0] = rs_w; ra.rs[1] = rs_c; ra.rs[2] = rs_b;
  int gSX = 0, gSC = 0, maxbin = 0;
  for (int y = 0; y < 3; ++y) {
    ra.nbin[y] = (ra.N[y] + 255) >> 8;
    ra.NB[y] = (ra.E[y] + EPB - 1) / EPB;
    if (ra.NB[y] > gSX) gSX = ra.NB[y];
    if (ra.nbin[y] > maxbin) maxbin = ra.nbin[y];
  }
  S3Args sa;
  sa.bsum[0] = bsum_w; sa.bsum[1] = bsum_c; sa.bsum[2] = bsum_b;
  for (int y = 0; y < 3; ++y) {
    sa.cnt[y] = ra.bh[y]; sa.rs[y] = ra.bhs[y];
    sa.n[y] = ra.nbin[y] * ra.NB[y];
    sa.nb[y] = (sa.n[y] + 1023) / 1024;
    if (sa.nb[y] > gSC) gSC = sa.nb[y];
  }

  // ---- fused layer args ----
  FLArgs f1, f2;
  f1.root[0] = xpb; f1.Wroot[0] = WF[3];
  f1.feat1[0] = xab; f1.Wrel1[0] = WF[0];
  f1.cnt1[0] = cnt_w; f1.rs1[0] = rs_w; f1.bkt1[0] = bkt_w;
  f1.feat2 = xpb; f1.Wrel2 = WF[1];
  f1.cnt2 = cnt_c; f1.rs2 = rs_c; f1.bkt2 = bkt_c;
  f1.bias[0] = b1rp; f1.out[0] = hp; f1.N[0] = NP;
  f1.root[1] = xab; f1.Wroot[1] = WF[4];
  f1.feat1[1] = xpb; f1.Wrel1[1] = WF[2];
  f1.cnt1[1] = cnt_b; f1.rs1[1] = rs_b; f1.bkt1[1] = bkt_b;
  f1.bias[1] = b1ra; f1.out[1] = ha; f1.N[1] = NA;
  f1.blocks0 = gP;
  f2.root[0] = hp; f2.Wroot[0] = WF[8];
  f2.feat1[0] = ha; f2.Wrel1[0] = WF[5];
  f2.cnt1[0] = cnt_w; f2.rs1[0] = rs_w; f2.bkt1[0] = bkt_w;
  f2.feat2 = hp; f2.Wrel2 = WF[6];
  f2.cnt2 = cnt_c; f2.rs2 = rs_c; f2.bkt2 = bkt_c;
  f2.bias[0] = b2rp; f2.out[0] = outP; f2.N[0] = NP;
  f2.root[1] = ha; f2.Wroot[1] = WF[9];
  f2.feat1[1] = hp; f2.Wrel1[1] = WF[7];
  f2.cnt1[1] = cnt_b; f2.rs1[1] = rs_b; f2.bkt1[1] = bkt_b;
  f2.bias[1] = b2ra; f2.out[1] = outA; f2.N[1] = NA;
  f2.blocks0 = gP;

  const int n4p = NP * DI / 4, n4a = NA * DI / 4;

  // ---- prep ----
  warrange_k<<<dim3(8, 10), 256, 0, stream>>>(wa);
  cvt2_k<<<(n4p + n4a + 255) / 256, 256, 0, stream>>>(xp, xpb, n4p, xa, xab, n4a);

  // ---- CSR build (no global atomics, no memsets) ----
  radix_s1_k<<<dim3(gSX, 3), 256, 0, stream>>>(ra);
  blocksum3_k<<<dim3(gSC, 3), 256, 0, stream>>>(sa);
  partials3_k<<<3, 256, 0, stream>>>(sa);
  scanwrite3_k<<<dim3(gSC, 3), 256, 0, stream>>>(sa);
  radix_x1_k<<<dim3(gSX, 3), 256, 0, stream>>>(ra);
  radix_p2_k<<<dim3(maxbin, 3), 256, 0, stream>>>(ra);

  // ---- fused layers ----
  fused_layer_k<128, true, true><<<gP + gA, 256, 0, stream>>>(f1);
  fused_layer_k<64, false, false><<<gP + gA, 256, 0, stream>>>(f2);
}

// Round 9
// 356.225 us; speedup vs baseline: 1.1039x; 1.0322x over previous
//
#include <hip/hip_runtime.h>

// RGCN 2-layer hetero graph conv. fp32 I/O, bf16 MFMA compute.
// R9: REVERT fusion (R7 LDS-fused 172us/layer, R8 reg-fused 168us/layer both
// lose to R6's split gather(88)+gemm(~33)); keep the lean radix CSR build.
// Gather and GEMM have opposed resource profiles: gather = 8-VGPR massive-TLP
// latency hiding (70% occ, 18750 blocks), GEMM = MFMA. Split wins.
// New: gather3 unroll-4 (4 x 16B edge loads in flight per lane, branchless
// clamp tail) to double memory-level parallelism in the latency-bound gather.

#define DI 128
#define NP 100000
#define NA 50000
#define EPB 4096
#define MAXBIN 391

typedef short s8v __attribute__((ext_vector_type(8)));
typedef float f32x4 __attribute__((ext_vector_type(4)));

__device__ __forceinline__ unsigned short bf16_rne(float f) {
  unsigned int fb = __float_as_uint(f);
  fb += 0x7FFFu + ((fb >> 16) & 1u);
  return (unsigned short)(fb >> 16);
}

// ---- fp32 -> bf16, both tables in one dispatch ----
__global__ __launch_bounds__(256) void cvt2_k(const float* __restrict__ Xp,
                                              unsigned short* __restrict__ Yp, int n4p,
                                              const float* __restrict__ Xa,
                                              unsigned short* __restrict__ Ya, int n4a) {
  int i = blockIdx.x * 256 + threadIdx.x;
  const float* X; unsigned short* Y;
  if (i < n4p) { X = Xp; Y = Yp; }
  else { i -= n4p; if (i >= n4a) return; X = Xa; Y = Ya; }
  float4 f = reinterpret_cast<const float4*>(X)[i];
  ushort4 o;
  o.x = bf16_rne(f.x); o.y = bf16_rne(f.y); o.z = bf16_rne(f.z); o.w = bf16_rne(f.w);
  reinterpret_cast<ushort4*>(Y)[i] = o;
}

// ==== radix CSR build (3 edge types via blockIdx.y) ====
struct R3Args {
  const int* src[3]; const int* dst[3];
  int* bh[3]; int* bhs[3];
  unsigned int* tmp[3];
  int* bkt[3]; int* cnt[3]; int* rs[3];
  int E[3]; int N[3]; int nbin[3]; int NB[3];
};

__global__ __launch_bounds__(256) void radix_s1_k(R3Args a) {
  int y = blockIdx.y, blk = blockIdx.x;
  int NB = a.NB[y];
  if (blk >= NB) return;
  __shared__ int hist[MAXBIN];
  int nbin = a.nbin[y];
  for (int i = threadIdx.x; i < nbin; i += 256) hist[i] = 0;
  __syncthreads();
  int e0 = blk * EPB, e1 = min(e0 + EPB, a.E[y]);
  const int* dst = a.dst[y];
  for (int e = e0 + threadIdx.x; e < e1; e += 256)
    atomicAdd(&hist[dst[e] >> 8], 1);
  __syncthreads();
  int* bh = a.bh[y];
  for (int i = threadIdx.x; i < nbin; i += 256) bh[i * NB + blk] = hist[i];
}

__global__ __launch_bounds__(256) void radix_x1_k(R3Args a) {
  int y = blockIdx.y, blk = blockIdx.x;
  int NB = a.NB[y];
  if (blk >= NB) return;
  __shared__ int cur[MAXBIN];
  int nbin = a.nbin[y];
  const int* bhs = a.bhs[y];
  for (int i = threadIdx.x; i < nbin; i += 256) cur[i] = bhs[i * NB + blk];
  __syncthreads();
  int e0 = blk * EPB, e1 = min(e0 + EPB, a.E[y]);
  const int* dst = a.dst[y];
  const int* src = a.src[y];
  unsigned int* tmp = a.tmp[y];
  for (int e = e0 + threadIdx.x; e < e1; e += 256) {
    int d = dst[e];
    int pos = atomicAdd(&cur[d >> 8], 1);
    tmp[pos] = ((unsigned int)(d & 255) << 24) | (unsigned int)src[e];
  }
}

__global__ __launch_bounds__(256) void radix_p2_k(R3Args a) {
  int y = blockIdx.y, bin = blockIdx.x;
  if (bin >= a.nbin[y]) return;
  __shared__ int hist[256], scn[256], cursor[256];
  int t = threadIdx.x;
  hist[t] = 0;
  __syncthreads();
  const int* bhs = a.bhs[y];
  int NB = a.NB[y];
  int base = bhs[bin * NB];
  int end  = (bin + 1 < a.nbin[y]) ? bhs[(bin + 1) * NB] : a.E[y];
  const unsigned int* tmp = a.tmp[y];
  for (int i = base + t; i < end; i += 256)
    atomicAdd(&hist[tmp[i] >> 24], 1);
  __syncthreads();
  int v = hist[t];
  scn[t] = v; __syncthreads();
  int acc = v;
  for (int o = 1; o < 256; o <<= 1) {
    int u = (t >= o) ? scn[t - o] : 0;
    __syncthreads();
    acc += u; scn[t] = acc;
    __syncthreads();
  }
  int ex = acc - v;
  cursor[t] = ex;
  int d = bin * 256 + t;
  if (d < a.N[y]) { a.cnt[y][d] = v; a.rs[y][d] = base + ex; }
  __syncthreads();
  int* bkt = a.bkt[y];
  for (int i = base + t; i < end; i += 256) {
    unsigned int p = tmp[i];
    int pos = atomicAdd(&cursor[p >> 24], 1);
    bkt[base + pos] = (int)(p & 0xFFFFFFu);
  }
}

// ==== hierarchical exclusive scan (for bh -> bhs) ====
struct S3Args {
  const int* cnt[3]; int* bsum[3]; int* rs[3];
  int n[3]; int nb[3];
};

__global__ __launch_bounds__(256) void blocksum3_k(S3Args a) {
  int y = blockIdx.y;
  int n = a.n[y];
  if (blockIdx.x * 1024 >= n) return;
  __shared__ int red[256];
  int t = threadIdx.x;
  int base = blockIdx.x * 1024 + t * 4;
  int s = 0;
  #pragma unroll
  for (int i = 0; i < 4; ++i) { int idx = base + i; if (idx < n) s += a.cnt[y][idx]; }
  red[t] = s; __syncthreads();
  #pragma unroll
  for (int o = 128; o > 0; o >>= 1) { if (t < o) red[t] += red[t + o]; __syncthreads(); }
  if (t == 0) a.bsum[y][blockIdx.x] = red[0];
}

__global__ __launch_bounds__(256) void partials3_k(S3Args a) {
  __shared__ int sm[256];
  int y = blockIdx.x;
  int nb = a.nb[y];
  int t = threadIdx.x;
  int v = (t < nb) ? a.bsum[y][t] : 0;
  sm[t] = v; __syncthreads();
  int acc = v;
  for (int o = 1; o < 256; o <<= 1) {
    int u = (t >= o) ? sm[t - o] : 0;
    __syncthreads();
    acc += u; sm[t] = acc;
    __syncthreads();
  }
  if (t < nb) a.bsum[y][t] = acc - v;  // exclusive
}

__global__ __launch_bounds__(256) void scanwrite3_k(S3Args a) {
  int y = blockIdx.y;
  int n = a.n[y];
  if (blockIdx.x * 1024 >= n) return;
  __shared__ int ts[256];
  int t = threadIdx.x;
  int base = blockIdx.x * 1024 + t * 4;
  int v[4]; int s = 0;
  #pragma unroll
  for (int i = 0; i < 4; ++i) { int idx = base + i; v[i] = (idx < n) ? a.cnt[y][idx] : 0; s += v[i]; }
  ts[t] = s; __syncthreads();
  int inc = s;
  for (int o = 1; o < 256; o <<= 1) {
    int u = (t >= o) ? ts[t - o] : 0;
    __syncthreads();
    inc += u; ts[t] = inc;
    __syncthreads();
  }
  int p = a.bsum[y][blockIdx.x] + inc - s;
  #pragma unroll
  for (int i = 0; i < 4; ++i) { int idx = base + i; if (idx < n) { a.rs[y][idx] = p; p += v[i]; } }
}

// ==== gather-max: 16 lanes/row (dwordx4), 4 rows/wave, 16 rows/block, 3-way y ====
// unroll-4: 4 edge loads (64B) in flight per lane; branchless clamp tail.
struct G3Args {
  const int* cnt[3]; const int* rs[3]; const int* bkt[3];
  const unsigned short* X[3]; unsigned short* S[3];
  int N[3];
};

__global__ __launch_bounds__(256) void gather3_k(G3Args a) {
  const int y = blockIdx.y;
  const int lane = threadIdx.x & 63;
  const int wave = threadIdx.x >> 6;
  const int g = lane >> 4, lg = lane & 15;
  const int d = blockIdx.x * 16 + wave * 4 + g;
  if (d >= a.N[y]) return;

  unsigned short* So = a.S[y] + (size_t)d * DI + lg * 8;
  const int deg = a.cnt[y][d];
  if (deg == 0) {
    uint4 z; z.x = z.y = z.z = z.w = 0u;
    *reinterpret_cast<uint4*>(So) = z;
    return;
  }
  const int* bp = a.bkt[y] + a.rs[y][d];
  const unsigned short* X = a.X[y];

  float ml[4], mh[4];
  #pragma unroll
  for (int j = 0; j < 4; ++j) { ml[j] = -3.4e38f; mh[j] = -3.4e38f; }

  int s0 = bp[0];
  for (int e = 0; e < deg; e += 4) {
    int s1 = (e + 1 < deg) ? bp[e + 1] : s0;   // branchless tail: re-max row 0
    int s2 = (e + 2 < deg) ? bp[e + 2] : s0;
    int s3 = (e + 3 < deg) ? bp[e + 3] : s0;
    int sn = (e + 4 < deg) ? bp[e + 4] : s0;
    uint4 r0 = *reinterpret_cast<const uint4*>(X + (size_t)s0 * DI + lg * 8);
    uint4 r1 = *reinterpret_cast<const uint4*>(X + (size_t)s1 * DI + lg * 8);
    uint4 r2 = *reinterpret_cast<const uint4*>(X + (size_t)s2 * DI + lg * 8);
    uint4 r3 = *reinterpret_cast<const uint4*>(X + (size_t)s3 * DI + lg * 8);
    unsigned int w0[4] = {r0.x, r0.y, r0.z, r0.w};
    unsigned int w1[4] = {r1.x, r1.y, r1.z, r1.w};
    unsigned int w2[4] = {r2.x, r2.y, r2.z, r2.w};
    unsigned int w3[4] = {r3.x, r3.y, r3.z, r3.w};
    #pragma unroll
    for (int j = 0; j < 4; ++j) {
      float a0 = fmaxf(__uint_as_float(w0[j] << 16), __uint_as_float(w1[j] << 16));
      float a1 = fmaxf(__uint_as_float(w2[j] << 16), __uint_as_float(w3[j] << 16));
      ml[j] = fmaxf(ml[j], fmaxf(a0, a1));
      float b0 = fmaxf(__uint_as_float(w0[j] & 0xFFFF0000u), __uint_as_float(w1[j] & 0xFFFF0000u));
      float b1 = fmaxf(__uint_as_float(w2[j] & 0xFFFF0000u), __uint_as_float(w3[j] & 0xFFFF0000u));
      mh[j] = fmaxf(mh[j], fmaxf(b0, b1));
    }
    s0 = sn;
  }
  uint4 o;
  o.x = (__float_as_uint(ml[0]) >> 16) | (__float_as_uint(mh[0]) & 0xFFFF0000u);
  o.y = (__float_as_uint(ml[1]) >> 16) | (__float_as_uint(mh[1]) & 0xFFFF0000u);
  o.z = (__float_as_uint(ml[2]) >> 16) | (__float_as_uint(mh[2]) & 0xFFFF0000u);
  o.w = (__float_as_uint(ml[3]) >> 16) | (__float_as_uint(mh[3]) & 0xFFFF0000u);
  *reinterpret_cast<uint4*>(So) = o;
}

// ---- weight rearrange (fp32 -> bf16 B-fragments): wf[((kc*CF+cf)*64+lane)*8+i]=W[k][c] ----
struct WArgs {
  const float* w[10];
  unsigned short* wf[10];
};
__global__ __launch_bounds__(256) void warrange_k(WArgs args) {
  int widx = blockIdx.y;
  int OUTi = (widx < 5) ? 128 : 64;
  int CF = OUTi / 16;
  int nt = 4 * CF * 64;
  int t = blockIdx.x * 256 + threadIdx.x;
  if (t >= nt) return;
  int lane = t & 63, tmp = t >> 6;
  int cf = tmp % CF, kc = tmp / CF;
  int k0 = kc * 32 + (lane >> 4) * 8;
  int c  = cf * 16 + (lane & 15);
  const float* w = args.w[widx];
  s8v v;
  #pragma unroll
  for (int i = 0; i < 8; ++i) v[i] = (short)bf16_rne(w[(k0 + i) * OUTi + c]);
  *(reinterpret_cast<s8v*>(args.wf[widx]) + t) = v;
}

// ==== fused GEMM pair: paper (3-src) blocks then author (2-src) blocks ====
// MFMA 16x16x32 bf16: A row=lane&15,k=(lane>>4)*8+i; B col=lane&15; D col=lane&15,row=(lane>>4)*4+reg
template<int CF>
__device__ __forceinline__ void mfma_accum(const unsigned short* __restrict__ A,
                                           const unsigned short* __restrict__ W,
                                           f32x4* acc, size_t arow, int lane, int half) {
  const s8v* a = reinterpret_cast<const s8v*>(A + arow * DI + half * 8);
  const s8v* w = reinterpret_cast<const s8v*>(W) + lane;
  #pragma unroll
  for (int kc = 0; kc < 4; ++kc) {
    s8v av = a[kc * 4];
    #pragma unroll
    for (int cf = 0; cf < CF; ++cf)
      acc[cf] = __builtin_amdgcn_mfma_f32_16x16x32_bf16(av, w[(kc * CF + cf) * 64], acc[cf], 0, 0, 0);
  }
}

struct GemmPairArgs {
  const unsigned short *A0[2], *W0[2], *A1[2], *W1[2], *A2, *W2;
  const float* bias[2];
  void* out[2];
  int N[2];
  int blocks0;
};

template<int OUT, bool RELU, bool OUT_BF16>
__global__ __launch_bounds__(256) void gemm_pair_k(GemmPairArgs g) {
  constexpr int CF = OUT / 16;
  const int p = (blockIdx.x >= (unsigned)g.blocks0) ? 1 : 0;
  const int brow = blockIdx.x - (p ? g.blocks0 : 0);
  const int N = g.N[p];
  const int lane = threadIdx.x & 63;
  const int wave = threadIdx.x >> 6;
  const int row0 = brow * 64 + wave * 16;
  if (row0 >= N) return;
  const int rl = lane & 15, half = lane >> 4;
  const size_t arow = (size_t)(row0 + rl);

  f32x4 acc[CF];
  #pragma unroll
  for (int i = 0; i < CF; ++i) acc[i] = f32x4{0.f, 0.f, 0.f, 0.f};

  mfma_accum<CF>(g.A0[p], g.W0[p], acc, arow, lane, half);
  mfma_accum<CF>(g.A1[p], g.W1[p], acc, arow, lane, half);
  if (!p) mfma_accum<CF>(g.A2, g.W2, acc, arow, lane, half);

  const float* bias = g.bias[p];
  #pragma unroll
  for (int cf = 0; cf < CF; ++cf) {
    float bv = bias[cf * 16 + rl];
    #pragma unroll
    for (int j = 0; j < 4; ++j) {
      int r = row0 + half * 4 + j;
      if (r >= N) continue;
      float v = acc[cf][j] + bv;
      if (RELU) v = v > 0.f ? v : 0.f;
      size_t idx = (size_t)r * OUT + cf * 16 + rl;
      if (OUT_BF16) ((unsigned short*)g.out[p])[idx] = bf16_rne(v);
      else          ((float*)g.out[p])[idx] = v;
    }
  }
}

extern "C" void kernel_launch(void* const* d_in, const int* in_sizes, int n_in,
                              void* d_out, int out_size, void* d_ws, size_t ws_size,
                              hipStream_t stream) {
  const float* xp = (const float*)d_in[0];
  const float* xa = (const float*)d_in[1];
  const int* wsrc = (const int*)d_in[2];
  const int* wdst = (const int*)d_in[3];
  const int* csrc = (const int*)d_in[4];
  const int* cdst = (const int*)d_in[5];
  const int* bsrc = (const int*)d_in[6];
  const int* bdst = (const int*)d_in[7];
  const int Ew = in_sizes[2], Ec = in_sizes[4], Eb = in_sizes[6];

  const float* w1w  = (const float*)d_in[8];
  const float* w1c  = (const float*)d_in[9];
  const float* w1wb = (const float*)d_in[10];
  const float* w1rp = (const float*)d_in[11];
  const float* b1rp = (const float*)d_in[12];
  const float* w1ra = (const float*)d_in[13];
  const float* b1ra = (const float*)d_in[14];
  const float* w2w  = (const float*)d_in[15];
  const float* w2c  = (const float*)d_in[16];
  const float* w2wb = (const float*)d_in[17];
  const float* w2rp = (const float*)d_in[18];
  const float* b2rp = (const float*)d_in[19];
  const float* w2ra = (const float*)d_in[20];
  const float* b2ra = (const float*)d_in[21];

  // ---- workspace layout (bytes) ----
  char* ws = (char*)d_ws;
  unsigned short* xpb = (unsigned short*)(ws + 0);           // 25,600,000
  unsigned short* xab = (unsigned short*)(ws + 25600000);    // 12,800,000
  unsigned short* hp  = (unsigned short*)(ws + 38400000);    // 25,600,000
  unsigned short* ha  = (unsigned short*)(ws + 64000000);    // 12,800,000
  unsigned short* S_w = (unsigned short*)(ws + 76800000);    // 25,600,000
  unsigned short* S_c = (unsigned short*)(ws + 102400000);   // 25,600,000
  unsigned short* S_b = (unsigned short*)(ws + 128000000);   // 12,800,000
  int* bkt_w = (int*)(ws + 140800000);                       // 3,200,000
  int* bkt_c = (int*)(ws + 144000000);                       // 3,200,000
  int* bkt_b = (int*)(ws + 147200000);                       // 3,200,000
  int* cnt_w = (int*)(ws + 150400000);                       // 400,000
  int* cnt_c = (int*)(ws + 150800000);                       // 400,000
  int* cnt_b = (int*)(ws + 151200000);                       // 200,000
  int* rs_w  = (int*)(ws + 151400000);                       // 400,000
  int* rs_c  = (int*)(ws + 151800000);                       // 400,000
  int* rs_b  = (int*)(ws + 152200000);                       // 200,000
  int* bsum_w = (int*)(ws + 152400000);                      // 4,096
  int* bsum_c = (int*)(ws + 152404096);                      // 4,096
  int* bsum_b = (int*)(ws + 152408192);                      // 4,096
  unsigned short* wf = (unsigned short*)(ws + 152412288);    // 245,760
  unsigned int* tmp_w = (unsigned int*)(ws + 152660000);     // 3,200,000
  unsigned int* tmp_c = (unsigned int*)(ws + 155860000);     // 3,200,000
  unsigned int* tmp_b = (unsigned int*)(ws + 159060000);     // 3,200,000
  // bh/bhs carved from S_w region (dead until first gather, which is after P2)
  int* bh_w  = (int*)(ws + 76800000);
  int* bh_c  = (int*)(ws + 77110000);
  int* bh_b  = (int*)(ws + 77420000);
  int* bhs_w = (int*)(ws + 77580000);
  int* bhs_c = (int*)(ws + 77890000);
  int* bhs_b = (int*)(ws + 78200000);

  unsigned short* WF[10];
  size_t off = 0;
  for (int i = 0; i < 10; ++i) {
    WF[i] = wf + off;
    off += (i < 5) ? (size_t)128 * 128 : (size_t)128 * 64;
  }
  WArgs wa;
  const float* wsrcs[10] = {w1w, w1c, w1wb, w1rp, w1ra, w2w, w2c, w2wb, w2rp, w2ra};
  for (int i = 0; i < 10; ++i) { wa.w[i] = wsrcs[i]; wa.wf[i] = WF[i]; }

  float* outP = (float*)d_out;              // 100000 x 64 fp32
  float* outA = outP + (size_t)NP * 64;     // 50000 x 64 fp32

  const int gP = (NP + 63) / 64, gA = (NA + 63) / 64;  // 1563, 782
  const int gG = (NP + 15) / 16;                       // 6250

  // ---- radix CSR args ----
  R3Args ra;
  ra.src[0] = wsrc; ra.dst[0] = wdst; ra.E[0] = Ew; ra.N[0] = NP;
  ra.src[1] = csrc; ra.dst[1] = cdst; ra.E[1] = Ec; ra.N[1] = NP;
  ra.src[2] = bsrc; ra.dst[2] = bdst; ra.E[2] = Eb; ra.N[2] = NA;
  ra.bh[0] = bh_w; ra.bh[1] = bh_c; ra.bh[2] = bh_b;
  ra.bhs[0] = bhs_w; ra.bhs[1] = bhs_c; ra.bhs[2] = bhs_b;
  ra.tmp[0] = tmp_w; ra.tmp[1] = tmp_c; ra.tmp[2] = tmp_b;
  ra.bkt[0] = bkt_w; ra.bkt[1] = bkt_c; ra.bkt[2] = bkt_b;
  ra.cnt[0] = cnt_w; ra.cnt[1] = cnt_c; ra.cnt[2] = cnt_b;
  ra.rs[0] = rs_w; ra.rs[1] = rs_c; ra.rs[2] = rs_b;
  int gSX = 0, gSC = 0, maxbin = 0;
  for (int y = 0; y < 3; ++y) {
    ra.nbin[y] = (ra.N[y] + 255) >> 8;
    ra.NB[y] = (ra.E[y] + EPB - 1) / EPB;
    if (ra.NB[y] > gSX) gSX = ra.NB[y];
    if (ra.nbin[y] > maxbin) maxbin = ra.nbin[y];
  }
  S3Args sa;
  sa.bsum[0] = bsum_w; sa.bsum[1] = bsum_c; sa.bsum[2] = bsum_b;
  for (int y = 0; y < 3; ++y) {
    sa.cnt[y] = ra.bh[y]; sa.rs[y] = ra.bhs[y];
    sa.n[y] = ra.nbin[y] * ra.NB[y];
    sa.nb[y] = (sa.n[y] + 1023) / 1024;
    if (sa.nb[y] > gSC) gSC = sa.nb[y];
  }

  G3Args g1, g2;
  for (int i = 0; i < 3; ++i) {
    g1.cnt[i] = g2.cnt[i] = (i == 0) ? cnt_w : (i == 1) ? cnt_c : cnt_b;
    g1.rs[i]  = g2.rs[i]  = (i == 0) ? rs_w  : (i == 1) ? rs_c  : rs_b;
    g1.bkt[i] = g2.bkt[i] = (i == 0) ? bkt_w : (i == 1) ? bkt_c : bkt_b;
    g1.S[i]   = g2.S[i]   = (i == 0) ? S_w   : (i == 1) ? S_c   : S_b;
    g1.N[i]   = g2.N[i]   = (i == 2) ? NA : NP;
  }
  g1.X[0] = xab; g1.X[1] = xpb; g1.X[2] = xpb;
  g2.X[0] = ha;  g2.X[1] = hp;  g2.X[2] = hp;

  GemmPairArgs p1, p2;
  p1.A0[0] = xpb; p1.W0[0] = WF[3]; p1.A1[0] = S_w; p1.W1[0] = WF[0]; p1.A2 = S_c; p1.W2 = WF[1];
  p1.bias[0] = b1rp; p1.out[0] = hp; p1.N[0] = NP;
  p1.A0[1] = xab; p1.W0[1] = WF[4]; p1.A1[1] = S_b; p1.W1[1] = WF[2];
  p1.bias[1] = b1ra; p1.out[1] = ha; p1.N[1] = NA;
  p1.blocks0 = gP;
  p2.A0[0] = hp; p2.W0[0] = WF[8]; p2.A1[0] = S_w; p2.W1[0] = WF[5]; p2.A2 = S_c; p2.W2 = WF[6];
  p2.bias[0] = b2rp; p2.out[0] = outP; p2.N[0] = NP;
  p2.A0[1] = ha; p2.W0[1] = WF[9]; p2.A1[1] = S_b; p2.W1[1] = WF[7];
  p2.bias[1] = b2ra; p2.out[1] = outA; p2.N[1] = NA;
  p2.blocks0 = gP;

  const int n4p = NP * DI / 4, n4a = NA * DI / 4;

  // ---- prep ----
  warrange_k<<<dim3(8, 10), 256, 0, stream>>>(wa);
  cvt2_k<<<(n4p + n4a + 255) / 256, 256, 0, stream>>>(xp, xpb, n4p, xa, xab, n4a);

  // ---- CSR build (no global atomics, no memsets) ----
  radix_s1_k<<<dim3(gSX, 3), 256, 0, stream>>>(ra);
  blocksum3_k<<<dim3(gSC, 3), 256, 0, stream>>>(sa);
  partials3_k<<<3, 256, 0, stream>>>(sa);
  scanwrite3_k<<<dim3(gSC, 3), 256, 0, stream>>>(sa);
  radix_x1_k<<<dim3(gSX, 3), 256, 0, stream>>>(ra);
  radix_p2_k<<<dim3(maxbin, 3), 256, 0, stream>>>(ra);

  // ---- layer 1 ----
  gather3_k<<<dim3(gG, 3), 256, 0, stream>>>(g1);
  gemm_pair_k<128, true, true><<<gP + gA, 256, 0, stream>>>(p1);

  // ---- layer 2 ----
  gather3_k<<<dim3(gG, 3), 256, 0, stream>>>(g2);
  gemm_pair_k<64, false, false><<<gP + gA, 256, 0, stream>>>(p2);
}

// Round 10
// 344.640 us; speedup vs baseline: 1.1410x; 1.0336x over previous
//
#include <hip/hip_runtime.h>

// RGCN 2-layer hetero graph conv. fp32 I/O, bf16 MFMA compute.
// R10: (1) gather VALU trim — bkt stores BYTE offsets (src*256), inner loop is
// one 64-bit add per load; fmax restructured as 3-ary trees for v_max3_f32.
// (2) cvt2 + warrange merged INTO the radix_p2 dispatch (single-stream kernel
// boundaries are barriers; cvt only feeds the gathers, so hiding it under p2
// removes ~25us of serial prep). 12 -> 10 dispatches.
// Structure: radix CSR (R6) + split gather/GEMM (R6/R9 — fusion loses, see R7/R8).

#define DI 128
#define NP 100000
#define NA 50000
#define EPB 4096
#define MAXBIN 391

typedef short s8v __attribute__((ext_vector_type(8)));
typedef float f32x4 __attribute__((ext_vector_type(4)));

__device__ __forceinline__ unsigned short bf16_rne(float f) {
  unsigned int fb = __float_as_uint(f);
  fb += 0x7FFFu + ((fb >> 16) & 1u);
  return (unsigned short)(fb >> 16);
}

// ==== radix CSR build (3 edge types via blockIdx.y) ====
struct R3Args {
  const int* src[3]; const int* dst[3];
  int* bh[3]; int* bhs[3];
  unsigned int* tmp[3];
  int* bkt[3]; int* cnt[3]; int* rs[3];
  int E[3]; int N[3]; int nbin[3]; int NB[3];
};

__global__ __launch_bounds__(256) void radix_s1_k(R3Args a) {
  int y = blockIdx.y, blk = blockIdx.x;
  int NB = a.NB[y];
  if (blk >= NB) return;
  __shared__ int hist[MAXBIN];
  int nbin = a.nbin[y];
  for (int i = threadIdx.x; i < nbin; i += 256) hist[i] = 0;
  __syncthreads();
  int e0 = blk * EPB, e1 = min(e0 + EPB, a.E[y]);
  const int* dst = a.dst[y];
  for (int e = e0 + threadIdx.x; e < e1; e += 256)
    atomicAdd(&hist[dst[e] >> 8], 1);
  __syncthreads();
  int* bh = a.bh[y];
  for (int i = threadIdx.x; i < nbin; i += 256) bh[i * NB + blk] = hist[i];
}

__global__ __launch_bounds__(256) void radix_x1_k(R3Args a) {
  int y = blockIdx.y, blk = blockIdx.x;
  int NB = a.NB[y];
  if (blk >= NB) return;
  __shared__ int cur[MAXBIN];
  int nbin = a.nbin[y];
  const int* bhs = a.bhs[y];
  for (int i = threadIdx.x; i < nbin; i += 256) cur[i] = bhs[i * NB + blk];
  __syncthreads();
  int e0 = blk * EPB, e1 = min(e0 + EPB, a.E[y]);
  const int* dst = a.dst[y];
  const int* src = a.src[y];
  unsigned int* tmp = a.tmp[y];
  for (int e = e0 + threadIdx.x; e < e1; e += 256) {
    int d = dst[e];
    int pos = atomicAdd(&cur[d >> 8], 1);
    tmp[pos] = ((unsigned int)(d & 255) << 24) | (unsigned int)src[e];
  }
}

// ---- weight rearrange args ----
struct WArgs {
  const float* w[10];
  unsigned short* wf[10];
};

// ==== merged: radix_p2 + weight rearrange + fp32->bf16 cvt (independent jobs,
// all must finish before gather-L1; merging hides cvt under p2) ====
struct P2CArgs {
  R3Args ra;
  WArgs wa;
  const float* Xp; unsigned short* Yp; int n4p;
  const float* Xa; unsigned short* Ya; int n4a;
  int p2Blocks;   // 3 * maxbin
  int maxbin;
};

__global__ __launch_bounds__(256) void p2cvt_k(P2CArgs a) {
  int bid = blockIdx.x;
  int t = threadIdx.x;
  if (bid < a.p2Blocks) {
    // ---- radix pass 2: per coarse bucket, LDS hist+scan of low byte ----
    int y = bid / a.maxbin, bin = bid % a.maxbin;
    if (bin >= a.ra.nbin[y]) return;
    __shared__ int hist[256], scn[256], cursor[256];
    hist[t] = 0;
    __syncthreads();
    const int* bhs = a.ra.bhs[y];
    int NB = a.ra.NB[y];
    int base = bhs[bin * NB];
    int end  = (bin + 1 < a.ra.nbin[y]) ? bhs[(bin + 1) * NB] : a.ra.E[y];
    const unsigned int* tmp = a.ra.tmp[y];
    for (int i = base + t; i < end; i += 256)
      atomicAdd(&hist[tmp[i] >> 24], 1);
    __syncthreads();
    int v = hist[t];
    scn[t] = v; __syncthreads();
    int acc = v;
    for (int o = 1; o < 256; o <<= 1) {
      int u = (t >= o) ? scn[t - o] : 0;
      __syncthreads();
      acc += u; scn[t] = acc;
      __syncthreads();
    }
    int ex = acc - v;
    cursor[t] = ex;
    int d = bin * 256 + t;
    if (d < a.ra.N[y]) { a.ra.cnt[y][d] = v; a.ra.rs[y][d] = base + ex; }
    __syncthreads();
    int* bkt = a.ra.bkt[y];
    for (int i = base + t; i < end; i += 256) {
      unsigned int p = tmp[i];
      int pos = atomicAdd(&cursor[p >> 24], 1);
      bkt[base + pos] = (int)((p & 0xFFFFFFu) << 8);  // BYTE offset: src * 256
    }
    return;
  }
  bid -= a.p2Blocks;
  if (bid < 80) {
    // ---- weight rearrange: wf[((kc*CF+cf)*64+lane)*8+i] = W[k][c] ----
    int widx = bid >> 3;
    int OUTi = (widx < 5) ? 128 : 64;
    int CF = OUTi / 16;
    int nt = 4 * CF * 64;
    int tg = (bid & 7) * 256 + t;
    if (tg >= nt) return;
    int lane = tg & 63, tmp2 = tg >> 6;
    int cf = tmp2 % CF, kc = tmp2 / CF;
    int k0 = kc * 32 + (lane >> 4) * 8;
    int c  = cf * 16 + (lane & 15);
    const float* w = a.wa.w[widx];
    s8v v;
    #pragma unroll
    for (int i = 0; i < 8; ++i) v[i] = (short)bf16_rne(w[(k0 + i) * OUTi + c]);
    *(reinterpret_cast<s8v*>(a.wa.wf[widx]) + tg) = v;
    return;
  }
  bid -= 80;
  // ---- fp32 -> bf16 cvt, 4 elems/thread ----
  int i = bid * 256 + t;
  const float* X; unsigned short* Y;
  if (i < a.n4p) { X = a.Xp; Y = a.Yp; }
  else { i -= a.n4p; if (i >= a.n4a) return; X = a.Xa; Y = a.Ya; }
  float4 f = reinterpret_cast<const float4*>(X)[i];
  ushort4 o;
  o.x = bf16_rne(f.x); o.y = bf16_rne(f.y); o.z = bf16_rne(f.z); o.w = bf16_rne(f.w);
  reinterpret_cast<ushort4*>(Y)[i] = o;
}

// ==== hierarchical exclusive scan (for bh -> bhs) ====
struct S3Args {
  const int* cnt[3]; int* bsum[3]; int* rs[3];
  int n[3]; int nb[3];
};

__global__ __launch_bounds__(256) void blocksum3_k(S3Args a) {
  int y = blockIdx.y;
  int n = a.n[y];
  if (blockIdx.x * 1024 >= n) return;
  __shared__ int red[256];
  int t = threadIdx.x;
  int base = blockIdx.x * 1024 + t * 4;
  int s = 0;
  #pragma unroll
  for (int i = 0; i < 4; ++i) { int idx = base + i; if (idx < n) s += a.cnt[y][idx]; }
  red[t] = s; __syncthreads();
  #pragma unroll
  for (int o = 128; o > 0; o >>= 1) { if (t < o) red[t] += red[t + o]; __syncthreads(); }
  if (t == 0) a.bsum[y][blockIdx.x] = red[0];
}

__global__ __launch_bounds__(256) void partials3_k(S3Args a) {
  __shared__ int sm[256];
  int y = blockIdx.x;
  int nb = a.nb[y];
  int t = threadIdx.x;
  int v = (t < nb) ? a.bsum[y][t] : 0;
  sm[t] = v; __syncthreads();
  int acc = v;
  for (int o = 1; o < 256; o <<= 1) {
    int u = (t >= o) ? sm[t - o] : 0;
    __syncthreads();
    acc += u; sm[t] = acc;
    __syncthreads();
  }
  if (t < nb) a.bsum[y][t] = acc - v;  // exclusive
}

__global__ __launch_bounds__(256) void scanwrite3_k(S3Args a) {
  int y = blockIdx.y;
  int n = a.n[y];
  if (blockIdx.x * 1024 >= n) return;
  __shared__ int ts[256];
  int t = threadIdx.x;
  int base = blockIdx.x * 1024 + t * 4;
  int v[4]; int s = 0;
  #pragma unroll
  for (int i = 0; i < 4; ++i) { int idx = base + i; v[i] = (idx < n) ? a.cnt[y][idx] : 0; s += v[i]; }
  ts[t] = s; __syncthreads();
  int inc = s;
  for (int o = 1; o < 256; o <<= 1) {
    int u = (t >= o) ? ts[t - o] : 0;
    __syncthreads();
    inc += u; ts[t] = inc;
    __syncthreads();
  }
  int p = a.bsum[y][blockIdx.x] + inc - s;
  #pragma unroll
  for (int i = 0; i < 4; ++i) { int idx = base + i; if (idx < n) { a.rs[y][idx] = p; p += v[i]; } }
}

// ==== gather-max: 16 lanes/row (dwordx4), 4 rows/wave, 16 rows/block, 3-way y ====
// bkt entries are BYTE offsets (src*256): 1 add per load. max via v_max3 trees.
struct G3Args {
  const int* cnt[3]; const int* rs[3]; const int* bkt[3];
  const unsigned short* X[3]; unsigned short* S[3];
  int N[3];
};

__global__ __launch_bounds__(256) void gather3_k(G3Args a) {
  const int y = blockIdx.y;
  const int lane = threadIdx.x & 63;
  const int wave = threadIdx.x >> 6;
  const int g = lane >> 4, lg = lane & 15;
  const int d = blockIdx.x * 16 + wave * 4 + g;
  if (d >= a.N[y]) return;

  unsigned short* So = a.S[y] + (size_t)d * DI + lg * 8;
  const int deg = a.cnt[y][d];
  if (deg == 0) {
    uint4 z; z.x = z.y = z.z = z.w = 0u;
    *reinterpret_cast<uint4*>(So) = z;
    return;
  }
  const int* bp = a.bkt[y] + a.rs[y][d];
  const char* Xb = reinterpret_cast<const char*>(a.X[y]) + lg * 16;

  float ml[4], mh[4];
  #pragma unroll
  for (int j = 0; j < 4; ++j) { ml[j] = -3.4e38f; mh[j] = -3.4e38f; }

  int s0 = bp[0];
  for (int e = 0; e < deg; e += 4) {
    int s1 = (e + 1 < deg) ? bp[e + 1] : s0;   // branchless tail: re-max row 0
    int s2 = (e + 2 < deg) ? bp[e + 2] : s0;
    int s3 = (e + 3 < deg) ? bp[e + 3] : s0;
    int sn = (e + 4 < deg) ? bp[e + 4] : s0;
    uint4 r0 = *reinterpret_cast<const uint4*>(Xb + s0);
    uint4 r1 = *reinterpret_cast<const uint4*>(Xb + s1);
    uint4 r2 = *reinterpret_cast<const uint4*>(Xb + s2);
    uint4 r3 = *reinterpret_cast<const uint4*>(Xb + s3);
    unsigned int w0[4] = {r0.x, r0.y, r0.z, r0.w};
    unsigned int w1[4] = {r1.x, r1.y, r1.z, r1.w};
    unsigned int w2[4] = {r2.x, r2.y, r2.z, r2.w};
    unsigned int w3[4] = {r3.x, r3.y, r3.z, r3.w};
    #pragma unroll
    for (int j = 0; j < 4; ++j) {
      // 3-ary trees -> v_max3_f32: max(max(a,b),c)
      float tl = fmaxf(fmaxf(__uint_as_float(w0[j] << 16), __uint_as_float(w1[j] << 16)),
                       __uint_as_float(w2[j] << 16));
      ml[j] = fmaxf(fmaxf(ml[j], __uint_as_float(w3[j] << 16)), tl);
      float th = fmaxf(fmaxf(__uint_as_float(w0[j] & 0xFFFF0000u), __uint_as_float(w1[j] & 0xFFFF0000u)),
                       __uint_as_float(w2[j] & 0xFFFF0000u));
      mh[j] = fmaxf(fmaxf(mh[j], __uint_as_float(w3[j] & 0xFFFF0000u)), th);
    }
    s0 = sn;
  }
  uint4 o;
  o.x = (__float_as_uint(ml[0]) >> 16) | (__float_as_uint(mh[0]) & 0xFFFF0000u);
  o.y = (__float_as_uint(ml[1]) >> 16) | (__float_as_uint(mh[1]) & 0xFFFF0000u);
  o.z = (__float_as_uint(ml[2]) >> 16) | (__float_as_uint(mh[2]) & 0xFFFF0000u);
  o.w = (__float_as_uint(ml[3]) >> 16) | (__float_as_uint(mh[3]) & 0xFFFF0000u);
  *reinterpret_cast<uint4*>(So) = o;
}

// ==== fused GEMM pair: paper (3-src) blocks then author (2-src) blocks ====
// MFMA 16x16x32 bf16: A row=lane&15,k=(lane>>4)*8+i; B col=lane&15; D col=lane&15,row=(lane>>4)*4+reg
template<int CF>
__device__ __forceinline__ void mfma_accum(const unsigned short* __restrict__ A,
                                           const unsigned short* __restrict__ W,
                                           f32x4* acc, size_t arow, int lane, int half) {
  const s8v* a = reinterpret_cast<const s8v*>(A + arow * DI + half * 8);
  const s8v* w = reinterpret_cast<const s8v*>(W) + lane;
  #pragma unroll
  for (int kc = 0; kc < 4; ++kc) {
    s8v av = a[kc * 4];
    #pragma unroll
    for (int cf = 0; cf < CF; ++cf)
      acc[cf] = __builtin_amdgcn_mfma_f32_16x16x32_bf16(av, w[(kc * CF + cf) * 64], acc[cf], 0, 0, 0);
  }
}

struct GemmPairArgs {
  const unsigned short *A0[2], *W0[2], *A1[2], *W1[2], *A2, *W2;
  const float* bias[2];
  void* out[2];
  int N[2];
  int blocks0;
};

template<int OUT, bool RELU, bool OUT_BF16>
__global__ __launch_bounds__(256) void gemm_pair_k(GemmPairArgs g) {
  constexpr int CF = OUT / 16;
  const int p = (blockIdx.x >= (unsigned)g.blocks0) ? 1 : 0;
  const int brow = blockIdx.x - (p ? g.blocks0 : 0);
  const int N = g.N[p];
  const int lane = threadIdx.x & 63;
  const int wave = threadIdx.x >> 6;
  const int row0 = brow * 64 + wave * 16;
  if (row0 >= N) return;
  const int rl = lane & 15, half = lane >> 4;
  const size_t arow = (size_t)(row0 + rl);

  f32x4 acc[CF];
  #pragma unroll
  for (int i = 0; i < CF; ++i) acc[i] = f32x4{0.f, 0.f, 0.f, 0.f};

  mfma_accum<CF>(g.A0[p], g.W0[p], acc, arow, lane, half);
  mfma_accum<CF>(g.A1[p], g.W1[p], acc, arow, lane, half);
  if (!p) mfma_accum<CF>(g.A2, g.W2, acc, arow, lane, half);

  const float* bias = g.bias[p];
  #pragma unroll
  for (int cf = 0; cf < CF; ++cf) {
    float bv = bias[cf * 16 + rl];
    #pragma unroll
    for (int j = 0; j < 4; ++j) {
      int r = row0 + half * 4 + j;
      if (r >= N) continue;
      float v = acc[cf][j] + bv;
      if (RELU) v = v > 0.f ? v : 0.f;
      size_t idx = (size_t)r * OUT + cf * 16 + rl;
      if (OUT_BF16) ((unsigned short*)g.out[p])[idx] = bf16_rne(v);
      else          ((float*)g.out[p])[idx] = v;
    }
  }
}

extern "C" void kernel_launch(void* const* d_in, const int* in_sizes, int n_in,
                              void* d_out, int out_size, void* d_ws, size_t ws_size,
                              hipStream_t stream) {
  const float* xp = (const float*)d_in[0];
  const float* xa = (const float*)d_in[1];
  const int* wsrc = (const int*)d_in[2];
  const int* wdst = (const int*)d_in[3];
  const int* csrc = (const int*)d_in[4];
  const int* cdst = (const int*)d_in[5];
  const int* bsrc = (const int*)d_in[6];
  const int* bdst = (const int*)d_in[7];
  const int Ew = in_sizes[2], Ec = in_sizes[4], Eb = in_sizes[6];

  const float* w1w  = (const float*)d_in[8];
  const float* w1c  = (const float*)d_in[9];
  const float* w1wb = (const float*)d_in[10];
  const float* w1rp = (const float*)d_in[11];
  const float* b1rp = (const float*)d_in[12];
  const float* w1ra = (const float*)d_in[13];
  const float* b1ra = (const float*)d_in[14];
  const float* w2w  = (const float*)d_in[15];
  const float* w2c  = (const float*)d_in[16];
  const float* w2wb = (const float*)d_in[17];
  const float* w2rp = (const float*)d_in[18];
  const float* b2rp = (const float*)d_in[19];
  const float* w2ra = (const float*)d_in[20];
  const float* b2ra = (const float*)d_in[21];

  // ---- workspace layout (bytes) ----
  char* ws = (char*)d_ws;
  unsigned short* xpb = (unsigned short*)(ws + 0);           // 25,600,000
  unsigned short* xab = (unsigned short*)(ws + 25600000);    // 12,800,000
  unsigned short* hp  = (unsigned short*)(ws + 38400000);    // 25,600,000
  unsigned short* ha  = (unsigned short*)(ws + 64000000);    // 12,800,000
  unsigned short* S_w = (unsigned short*)(ws + 76800000);    // 25,600,000
  unsigned short* S_c = (unsigned short*)(ws + 102400000);   // 25,600,000
  unsigned short* S_b = (unsigned short*)(ws + 128000000);   // 12,800,000
  int* bkt_w = (int*)(ws + 140800000);                       // 3,200,000
  int* bkt_c = (int*)(ws + 144000000);                       // 3,200,000
  int* bkt_b = (int*)(ws + 147200000);                       // 3,200,000
  int* cnt_w = (int*)(ws + 150400000);                       // 400,000
  int* cnt_c = (int*)(ws + 150800000);                       // 400,000
  int* cnt_b = (int*)(ws + 151200000);                       // 200,000
  int* rs_w  = (int*)(ws + 151400000);                       // 400,000
  int* rs_c  = (int*)(ws + 151800000);                       // 400,000
  int* rs_b  = (int*)(ws + 152200000);                       // 200,000
  int* bsum_w = (int*)(ws + 152400000);                      // 4,096
  int* bsum_c = (int*)(ws + 152404096);                      // 4,096
  int* bsum_b = (int*)(ws + 152408192);                      // 4,096
  unsigned short* wf = (unsigned short*)(ws + 152412288);    // 245,760
  unsigned int* tmp_w = (unsigned int*)(ws + 152660000);     // 3,200,000
  unsigned int* tmp_c = (unsigned int*)(ws + 155860000);     // 3,200,000
  unsigned int* tmp_b = (unsigned int*)(ws + 159060000);     // 3,200,000
  // bh/bhs carved from S_w region (dead until first gather, which is after p2cvt)
  int* bh_w  = (int*)(ws + 76800000);
  int* bh_c  = (int*)(ws + 77110000);
  int* bh_b  = (int*)(ws + 77420000);
  int* bhs_w = (int*)(ws + 77580000);
  int* bhs_c = (int*)(ws + 77890000);
  int* bhs_b = (int*)(ws + 78200000);

  unsigned short* WF[10];
  size_t off = 0;
  for (int i = 0; i < 10; ++i) {
    WF[i] = wf + off;
    off += (i < 5) ? (size_t)128 * 128 : (size_t)128 * 64;
  }

  float* outP = (float*)d_out;              // 100000 x 64 fp32
  float* outA = outP + (size_t)NP * 64;     // 50000 x 64 fp32

  const int gP = (NP + 63) / 64, gA = (NA + 63) / 64;  // 1563, 782
  const int gG = (NP + 15) / 16;                       // 6250

  // ---- radix CSR args ----
  R3Args ra;
  ra.src[0] = wsrc; ra.dst[0] = wdst; ra.E[0] = Ew; ra.N[0] = NP;
  ra.src[1] = csrc; ra.dst[1] = cdst; ra.E[1] = Ec; ra.N[1] = NP;
  ra.src[2] = bsrc; ra.dst[2] = bdst; ra.E[2] = Eb; ra.N[2] = NA;
  ra.bh[0] = bh_w; ra.bh[1] = bh_c; ra.bh[2] = bh_b;
  ra.bhs[0] = bhs_w; ra.bhs[1] = bhs_c; ra.bhs[2] = bhs_b;
  ra.tmp[0] = tmp_w; ra.tmp[1] = tmp_c; ra.tmp[2] = tmp_b;
  ra.bkt[0] = bkt_w; ra.bkt[1] = bkt_c; ra.bkt[2] = bkt_b;
  ra.cnt[0] = cnt_w; ra.cnt[1] = cnt_c; ra.cnt[2] = cnt_b;
  ra.rs[0] = rs_w; ra.rs[1] = rs_c; ra.rs[2] = rs_b;
  int gSX = 0, gSC = 0, maxbin = 0;
  for (int y = 0; y < 3; ++y) {
    ra.nbin[y] = (ra.N[y] + 255) >> 8;
    ra.NB[y] = (ra.E[y] + EPB - 1) / EPB;
    if (ra.NB[y] > gSX) gSX = ra.NB[y];
    if (ra.nbin[y] > maxbin) maxbin = ra.nbin[y];
  }
  S3Args sa;
  sa.bsum[0] = bsum_w; sa.bsum[1] = bsum_c; sa.bsum[2] = bsum_b;
  for (int y = 0; y < 3; ++y) {
    sa.cnt[y] = ra.bh[y]; sa.rs[y] = ra.bhs[y];
    sa.n[y] = ra.nbin[y] * ra.NB[y];
    sa.nb[y] = (sa.n[y] + 1023) / 1024;
    if (sa.nb[y] > gSC) gSC = sa.nb[y];
  }

  // ---- merged p2 + warrange + cvt args ----
  const int n4p = NP * DI / 4, n4a = NA * DI / 4;
  P2CArgs pc;
  pc.ra = ra;
  const float* wsrcs[10] = {w1w, w1c, w1wb, w1rp, w1ra, w2w, w2c, w2wb, w2rp, w2ra};
  for (int i = 0; i < 10; ++i) { pc.wa.w[i] = wsrcs[i]; pc.wa.wf[i] = WF[i]; }
  pc.Xp = xp; pc.Yp = xpb; pc.n4p = n4p;
  pc.Xa = xa; pc.Ya = xab; pc.n4a = n4a;
  pc.maxbin = maxbin;
  pc.p2Blocks = 3 * maxbin;
  const int gPC = pc.p2Blocks + 80 + (n4p + n4a + 255) / 256;

  G3Args g1, g2;
  for (int i = 0; i < 3; ++i) {
    g1.cnt[i] = g2.cnt[i] = (i == 0) ? cnt_w : (i == 1) ? cnt_c : cnt_b;
    g1.rs[i]  = g2.rs[i]  = (i == 0) ? rs_w  : (i == 1) ? rs_c  : rs_b;
    g1.bkt[i] = g2.bkt[i] = (i == 0) ? bkt_w : (i == 1) ? bkt_c : bkt_b;
    g1.S[i]   = g2.S[i]   = (i == 0) ? S_w   : (i == 1) ? S_c   : S_b;
    g1.N[i]   = g2.N[i]   = (i == 2) ? NA : NP;
  }
  g1.X[0] = xab; g1.X[1] = xpb; g1.X[2] = xpb;
  g2.X[0] = ha;  g2.X[1] = hp;  g2.X[2] = hp;

  GemmPairArgs p1, p2;
  p1.A0[0] = xpb; p1.W0[0] = WF[3]; p1.A1[0] = S_w; p1.W1[0] = WF[0]; p1.A2 = S_c; p1.W2 = WF[1];
  p1.bias[0] = b1rp; p1.out[0] = hp; p1.N[0] = NP;
  p1.A0[1] = xab; p1.W0[1] = WF[4]; p1.A1[1] = S_b; p1.W1[1] = WF[2];
  p1.bias[1] = b1ra; p1.out[1] = ha; p1.N[1] = NA;
  p1.blocks0 = gP;
  p2.A0[0] = hp; p2.W0[0] = WF[8]; p2.A1[0] = S_w; p2.W1[0] = WF[5]; p2.A2 = S_c; p2.W2 = WF[6];
  p2.bias[0] = b2rp; p2.out[0] = outP; p2.N[0] = NP;
  p2.A0[1] = ha; p2.W0[1] = WF[9]; p2.A1[1] = S_b; p2.W1[1] = WF[7];
  p2.bias[1] = b2ra; p2.out[1] = outA; p2.N[1] = NA;
  p2.blocks0 = gP;

  // ---- CSR build + prep (no global atomics, no memsets) ----
  radix_s1_k<<<dim3(gSX, 3), 256, 0, stream>>>(ra);
  blocksum3_k<<<dim3(gSC, 3), 256, 0, stream>>>(sa);
  partials3_k<<<3, 256, 0, stream>>>(sa);
  scanwrite3_k<<<dim3(gSC, 3), 256, 0, stream>>>(sa);
  radix_x1_k<<<dim3(gSX, 3), 256, 0, stream>>>(ra);
  p2cvt_k<<<gPC, 256, 0, stream>>>(pc);   // p2 + weight rearrange + bf16 cvt

  // ---- layer 1 ----
  gather3_k<<<dim3(gG, 3), 256, 0, stream>>>(g1);
  gemm_pair_k<128, true, true><<<gP + gA, 256, 0, stream>>>(p1);

  // ---- layer 2 ----
  gather3_k<<<dim3(gG, 3), 256, 0, stream>>>(g2);
  gemm_pair_k<64, false, false><<<gP + gA, 256, 0, stream>>>(p2);
}

// Round 11
// 334.517 us; speedup vs baseline: 1.1755x; 1.0303x over previous
//
#include <hip/hip_runtime.h>

// RGCN 2-layer hetero graph conv. fp32 I/O, bf16 MFMA compute.
// R11: gather inner-loop VALU cut — hi-half max computed by fmax on the RAW
// packed word as float (low 16 bits perturb < 1 ulp of the hi bf16, so the
// truncated max is exact; distinct-hi ordering preserved, equal-hi truncates
// identically). Removes the &0xFFFF0000 per word. Plus nontemporal stores for
// the final fp32 outputs (never re-read). Structure unchanged from R10:
// radix CSR (zero global atomics) + merged prep + split gather/GEMM.

#define DI 128
#define NP 100000
#define NA 50000
#define EPB 4096
#define MAXBIN 391

typedef short s8v __attribute__((ext_vector_type(8)));
typedef float f32x4 __attribute__((ext_vector_type(4)));

__device__ __forceinline__ unsigned short bf16_rne(float f) {
  unsigned int fb = __float_as_uint(f);
  fb += 0x7FFFu + ((fb >> 16) & 1u);
  return (unsigned short)(fb >> 16);
}

// ==== radix CSR build (3 edge types via blockIdx.y) ====
struct R3Args {
  const int* src[3]; const int* dst[3];
  int* bh[3]; int* bhs[3];
  unsigned int* tmp[3];
  int* bkt[3]; int* cnt[3]; int* rs[3];
  int E[3]; int N[3]; int nbin[3]; int NB[3];
};

__global__ __launch_bounds__(256) void radix_s1_k(R3Args a) {
  int y = blockIdx.y, blk = blockIdx.x;
  int NB = a.NB[y];
  if (blk >= NB) return;
  __shared__ int hist[MAXBIN];
  int nbin = a.nbin[y];
  for (int i = threadIdx.x; i < nbin; i += 256) hist[i] = 0;
  __syncthreads();
  int e0 = blk * EPB, e1 = min(e0 + EPB, a.E[y]);
  const int* dst = a.dst[y];
  for (int e = e0 + threadIdx.x; e < e1; e += 256)
    atomicAdd(&hist[dst[e] >> 8], 1);
  __syncthreads();
  int* bh = a.bh[y];
  for (int i = threadIdx.x; i < nbin; i += 256) bh[i * NB + blk] = hist[i];
}

__global__ __launch_bounds__(256) void radix_x1_k(R3Args a) {
  int y = blockIdx.y, blk = blockIdx.x;
  int NB = a.NB[y];
  if (blk >= NB) return;
  __shared__ int cur[MAXBIN];
  int nbin = a.nbin[y];
  const int* bhs = a.bhs[y];
  for (int i = threadIdx.x; i < nbin; i += 256) cur[i] = bhs[i * NB + blk];
  __syncthreads();
  int e0 = blk * EPB, e1 = min(e0 + EPB, a.E[y]);
  const int* dst = a.dst[y];
  const int* src = a.src[y];
  unsigned int* tmp = a.tmp[y];
  for (int e = e0 + threadIdx.x; e < e1; e += 256) {
    int d = dst[e];
    int pos = atomicAdd(&cur[d >> 8], 1);
    tmp[pos] = ((unsigned int)(d & 255) << 24) | (unsigned int)src[e];
  }
}

// ---- weight rearrange args ----
struct WArgs {
  const float* w[10];
  unsigned short* wf[10];
};

// ==== merged: radix_p2 + weight rearrange + fp32->bf16 cvt ====
struct P2CArgs {
  R3Args ra;
  WArgs wa;
  const float* Xp; unsigned short* Yp; int n4p;
  const float* Xa; unsigned short* Ya; int n4a;
  int p2Blocks;   // 3 * maxbin
  int maxbin;
};

__global__ __launch_bounds__(256) void p2cvt_k(P2CArgs a) {
  int bid = blockIdx.x;
  int t = threadIdx.x;
  if (bid < a.p2Blocks) {
    // ---- radix pass 2: per coarse bucket, LDS hist+scan of low byte ----
    int y = bid / a.maxbin, bin = bid % a.maxbin;
    if (bin >= a.ra.nbin[y]) return;
    __shared__ int hist[256], scn[256], cursor[256];
    hist[t] = 0;
    __syncthreads();
    const int* bhs = a.ra.bhs[y];
    int NB = a.ra.NB[y];
    int base = bhs[bin * NB];
    int end  = (bin + 1 < a.ra.nbin[y]) ? bhs[(bin + 1) * NB] : a.ra.E[y];
    const unsigned int* tmp = a.ra.tmp[y];
    for (int i = base + t; i < end; i += 256)
      atomicAdd(&hist[tmp[i] >> 24], 1);
    __syncthreads();
    int v = hist[t];
    scn[t] = v; __syncthreads();
    int acc = v;
    for (int o = 1; o < 256; o <<= 1) {
      int u = (t >= o) ? scn[t - o] : 0;
      __syncthreads();
      acc += u; scn[t] = acc;
      __syncthreads();
    }
    int ex = acc - v;
    cursor[t] = ex;
    int d = bin * 256 + t;
    if (d < a.ra.N[y]) { a.ra.cnt[y][d] = v; a.ra.rs[y][d] = base + ex; }
    __syncthreads();
    int* bkt = a.ra.bkt[y];
    for (int i = base + t; i < end; i += 256) {
      unsigned int p = tmp[i];
      int pos = atomicAdd(&cursor[p >> 24], 1);
      bkt[base + pos] = (int)((p & 0xFFFFFFu) << 8);  // BYTE offset: src * 256
    }
    return;
  }
  bid -= a.p2Blocks;
  if (bid < 80) {
    // ---- weight rearrange: wf[((kc*CF+cf)*64+lane)*8+i] = W[k][c] ----
    int widx = bid >> 3;
    int OUTi = (widx < 5) ? 128 : 64;
    int CF = OUTi / 16;
    int nt = 4 * CF * 64;
    int tg = (bid & 7) * 256 + t;
    if (tg >= nt) return;
    int lane = tg & 63, tmp2 = tg >> 6;
    int cf = tmp2 % CF, kc = tmp2 / CF;
    int k0 = kc * 32 + (lane >> 4) * 8;
    int c  = cf * 16 + (lane & 15);
    const float* w = a.wa.w[widx];
    s8v v;
    #pragma unroll
    for (int i = 0; i < 8; ++i) v[i] = (short)bf16_rne(w[(k0 + i) * OUTi + c]);
    *(reinterpret_cast<s8v*>(a.wa.wf[widx]) + tg) = v;
    return;
  }
  bid -= 80;
  // ---- fp32 -> bf16 cvt, 4 elems/thread ----
  int i = bid * 256 + t;
  const float* X; unsigned short* Y;
  if (i < a.n4p) { X = a.Xp; Y = a.Yp; }
  else { i -= a.n4p; if (i >= a.n4a) return; X = a.Xa; Y = a.Ya; }
  float4 f = reinterpret_cast<const float4*>(X)[i];
  ushort4 o;
  o.x = bf16_rne(f.x); o.y = bf16_rne(f.y); o.z = bf16_rne(f.z); o.w = bf16_rne(f.w);
  reinterpret_cast<ushort4*>(Y)[i] = o;
}

// ==== hierarchical exclusive scan (for bh -> bhs) ====
struct S3Args {
  const int* cnt[3]; int* bsum[3]; int* rs[3];
  int n[3]; int nb[3];
};

__global__ __launch_bounds__(256) void blocksum3_k(S3Args a) {
  int y = blockIdx.y;
  int n = a.n[y];
  if (blockIdx.x * 1024 >= n) return;
  __shared__ int red[256];
  int t = threadIdx.x;
  int base = blockIdx.x * 1024 + t * 4;
  int s = 0;
  #pragma unroll
  for (int i = 0; i < 4; ++i) { int idx = base + i; if (idx < n) s += a.cnt[y][idx]; }
  red[t] = s; __syncthreads();
  #pragma unroll
  for (int o = 128; o > 0; o >>= 1) { if (t < o) red[t] += red[t + o]; __syncthreads(); }
  if (t == 0) a.bsum[y][blockIdx.x] = red[0];
}

__global__ __launch_bounds__(256) void partials3_k(S3Args a) {
  __shared__ int sm[256];
  int y = blockIdx.x;
  int nb = a.nb[y];
  int t = threadIdx.x;
  int v = (t < nb) ? a.bsum[y][t] : 0;
  sm[t] = v; __syncthreads();
  int acc = v;
  for (int o = 1; o < 256; o <<= 1) {
    int u = (t >= o) ? sm[t - o] : 0;
    __syncthreads();
    acc += u; sm[t] = acc;
    __syncthreads();
  }
  if (t < nb) a.bsum[y][t] = acc - v;  // exclusive
}

__global__ __launch_bounds__(256) void scanwrite3_k(S3Args a) {
  int y = blockIdx.y;
  int n = a.n[y];
  if (blockIdx.x * 1024 >= n) return;
  __shared__ int ts[256];
  int t = threadIdx.x;
  int base = blockIdx.x * 1024 + t * 4;
  int v[4]; int s = 0;
  #pragma unroll
  for (int i = 0; i < 4; ++i) { int idx = base + i; v[i] = (idx < n) ? a.cnt[y][idx] : 0; s += v[i]; }
  ts[t] = s; __syncthreads();
  int inc = s;
  for (int o = 1; o < 256; o <<= 1) {
    int u = (t >= o) ? ts[t - o] : 0;
    __syncthreads();
    inc += u; ts[t] = inc;
    __syncthreads();
  }
  int p = a.bsum[y][blockIdx.x] + inc - s;
  #pragma unroll
  for (int i = 0; i < 4; ++i) { int idx = base + i; if (idx < n) { a.rs[y][idx] = p; p += v[i]; } }
}

// ==== gather-max: 16 lanes/row (dwordx4), 4 rows/wave, 16 rows/block, 3-way y ====
// bkt entries are BYTE offsets. Low-half max: fmax(word<<16). High-half max:
// fmax on the RAW word as float — low bits perturb < 1 ulp of the hi bf16, so
// ordering of distinct hi values is preserved and truncation is exact.
struct G3Args {
  const int* cnt[3]; const int* rs[3]; const int* bkt[3];
  const unsigned short* X[3]; unsigned short* S[3];
  int N[3];
};

__global__ __launch_bounds__(256) void gather3_k(G3Args a) {
  const int y = blockIdx.y;
  const int lane = threadIdx.x & 63;
  const int wave = threadIdx.x >> 6;
  const int g = lane >> 4, lg = lane & 15;
  const int d = blockIdx.x * 16 + wave * 4 + g;
  if (d >= a.N[y]) return;

  unsigned short* So = a.S[y] + (size_t)d * DI + lg * 8;
  const int deg = a.cnt[y][d];
  if (deg == 0) {
    uint4 z; z.x = z.y = z.z = z.w = 0u;
    *reinterpret_cast<uint4*>(So) = z;
    return;
  }
  const int* bp = a.bkt[y] + a.rs[y][d];
  const char* Xb = reinterpret_cast<const char*>(a.X[y]) + lg * 16;

  float ml[4], mh[4];
  #pragma unroll
  for (int j = 0; j < 4; ++j) { ml[j] = -3.4e38f; mh[j] = -3.4e38f; }

  int s0 = bp[0];
  for (int e = 0; e < deg; e += 4) {
    int s1 = (e + 1 < deg) ? bp[e + 1] : s0;   // branchless tail: re-max row 0
    int s2 = (e + 2 < deg) ? bp[e + 2] : s0;
    int s3 = (e + 3 < deg) ? bp[e + 3] : s0;
    int sn = (e + 4 < deg) ? bp[e + 4] : s0;
    uint4 r0 = *reinterpret_cast<const uint4*>(Xb + s0);
    uint4 r1 = *reinterpret_cast<const uint4*>(Xb + s1);
    uint4 r2 = *reinterpret_cast<const uint4*>(Xb + s2);
    uint4 r3 = *reinterpret_cast<const uint4*>(Xb + s3);
    unsigned int w0[4] = {r0.x, r0.y, r0.z, r0.w};
    unsigned int w1[4] = {r1.x, r1.y, r1.z, r1.w};
    unsigned int w2[4] = {r2.x, r2.y, r2.z, r2.w};
    unsigned int w3[4] = {r3.x, r3.y, r3.z, r3.w};
    #pragma unroll
    for (int j = 0; j < 4; ++j) {
      // low halves (shift up)
      float tl = fmaxf(fmaxf(__uint_as_float(w0[j] << 16), __uint_as_float(w1[j] << 16)),
                       __uint_as_float(w2[j] << 16));
      ml[j] = fmaxf(fmaxf(ml[j], __uint_as_float(w3[j] << 16)), tl);
      // high halves: RAW word as float (no mask — see header comment)
      float th = fmaxf(fmaxf(__uint_as_float(w0[j]), __uint_as_float(w1[j])),
                       __uint_as_float(w2[j]));
      mh[j] = fmaxf(fmaxf(mh[j], __uint_as_float(w3[j])), th);
    }
    s0 = sn;
  }
  uint4 o;
  o.x = (__float_as_uint(ml[0]) >> 16) | (__float_as_uint(mh[0]) & 0xFFFF0000u);
  o.y = (__float_as_uint(ml[1]) >> 16) | (__float_as_uint(mh[1]) & 0xFFFF0000u);
  o.z = (__float_as_uint(ml[2]) >> 16) | (__float_as_uint(mh[2]) & 0xFFFF0000u);
  o.w = (__float_as_uint(ml[3]) >> 16) | (__float_as_uint(mh[3]) & 0xFFFF0000u);
  *reinterpret_cast<uint4*>(So) = o;
}

// ==== fused GEMM pair: paper (3-src) blocks then author (2-src) blocks ====
// MFMA 16x16x32 bf16: A row=lane&15,k=(lane>>4)*8+i; B col=lane&15; D col=lane&15,row=(lane>>4)*4+reg
template<int CF>
__device__ __forceinline__ void mfma_accum(const unsigned short* __restrict__ A,
                                           const unsigned short* __restrict__ W,
                                           f32x4* acc, size_t arow, int lane, int half) {
  const s8v* a = reinterpret_cast<const s8v*>(A + arow * DI + half * 8);
  const s8v* w = reinterpret_cast<const s8v*>(W) + lane;
  #pragma unroll
  for (int kc = 0; kc < 4; ++kc) {
    s8v av = a[kc * 4];
    #pragma unroll
    for (int cf = 0; cf < CF; ++cf)
      acc[cf] = __builtin_amdgcn_mfma_f32_16x16x32_bf16(av, w[(kc * CF + cf) * 64], acc[cf], 0, 0, 0);
  }
}

struct GemmPairArgs {
  const unsigned short *A0[2], *W0[2], *A1[2], *W1[2], *A2, *W2;
  const float* bias[2];
  void* out[2];
  int N[2];
  int blocks0;
};

template<int OUT, bool RELU, bool OUT_BF16>
__global__ __launch_bounds__(256) void gemm_pair_k(GemmPairArgs g) {
  constexpr int CF = OUT / 16;
  const int p = (blockIdx.x >= (unsigned)g.blocks0) ? 1 : 0;
  const int brow = blockIdx.x - (p ? g.blocks0 : 0);
  const int N = g.N[p];
  const int lane = threadIdx.x & 63;
  const int wave = threadIdx.x >> 6;
  const int row0 = brow * 64 + wave * 16;
  if (row0 >= N) return;
  const int rl = lane & 15, half = lane >> 4;
  const size_t arow = (size_t)(row0 + rl);

  f32x4 acc[CF];
  #pragma unroll
  for (int i = 0; i < CF; ++i) acc[i] = f32x4{0.f, 0.f, 0.f, 0.f};

  mfma_accum<CF>(g.A0[p], g.W0[p], acc, arow, lane, half);
  mfma_accum<CF>(g.A1[p], g.W1[p], acc, arow, lane, half);
  if (!p) mfma_accum<CF>(g.A2, g.W2, acc, arow, lane, half);

  const float* bias = g.bias[p];
  #pragma unroll
  for (int cf = 0; cf < CF; ++cf) {
    float bv = bias[cf * 16 + rl];
    #pragma unroll
    for (int j = 0; j < 4; ++j) {
      int r = row0 + half * 4 + j;
      if (r >= N) continue;
      float v = acc[cf][j] + bv;
      if (RELU) v = v > 0.f ? v : 0.f;
      size_t idx = (size_t)r * OUT + cf * 16 + rl;
      if (OUT_BF16) ((unsigned short*)g.out[p])[idx] = bf16_rne(v);
      else          __builtin_nontemporal_store(v, (float*)g.out[p] + idx);  // final out: never re-read
    }
  }
}

extern "C" void kernel_launch(void* const* d_in, const int* in_sizes, int n_in,
                              void* d_out, int out_size, void* d_ws, size_t ws_size,
                              hipStream_t stream) {
  const float* xp = (const float*)d_in[0];
  const float* xa = (const float*)d_in[1];
  const int* wsrc = (const int*)d_in[2];
  const int* wdst = (const int*)d_in[3];
  const int* csrc = (const int*)d_in[4];
  const int* cdst = (const int*)d_in[5];
  const int* bsrc = (const int*)d_in[6];
  const int* bdst = (const int*)d_in[7];
  const int Ew = in_sizes[2], Ec = in_sizes[4], Eb = in_sizes[6];

  const float* w1w  = (const float*)d_in[8];
  const float* w1c  = (const float*)d_in[9];
  const float* w1wb = (const float*)d_in[10];
  const float* w1rp = (const float*)d_in[11];
  const float* b1rp = (const float*)d_in[12];
  const float* w1ra = (const float*)d_in[13];
  const float* b1ra = (const float*)d_in[14];
  const float* w2w  = (const float*)d_in[15];
  const float* w2c  = (const float*)d_in[16];
  const float* w2wb = (const float*)d_in[17];
  const float* w2rp = (const float*)d_in[18];
  const float* b2rp = (const float*)d_in[19];
  const float* w2ra = (const float*)d_in[20];
  const float* b2ra = (const float*)d_in[21];

  // ---- workspace layout (bytes) ----
  char* ws = (char*)d_ws;
  unsigned short* xpb = (unsigned short*)(ws + 0);           // 25,600,000
  unsigned short* xab = (unsigned short*)(ws + 25600000);    // 12,800,000
  unsigned short* hp  = (unsigned short*)(ws + 38400000);    // 25,600,000
  unsigned short* ha  = (unsigned short*)(ws + 64000000);    // 12,800,000
  unsigned short* S_w = (unsigned short*)(ws + 76800000);    // 25,600,000
  unsigned short* S_c = (unsigned short*)(ws + 102400000);   // 25,600,000
  unsigned short* S_b = (unsigned short*)(ws + 128000000);   // 12,800,000
  int* bkt_w = (int*)(ws + 140800000);                       // 3,200,000
  int* bkt_c = (int*)(ws + 144000000);                       // 3,200,000
  int* bkt_b = (int*)(ws + 147200000);                       // 3,200,000
  int* cnt_w = (int*)(ws + 150400000);                       // 400,000
  int* cnt_c = (int*)(ws + 150800000);                       // 400,000
  int* cnt_b = (int*)(ws + 151200000);                       // 200,000
  int* rs_w  = (int*)(ws + 151400000);                       // 400,000
  int* rs_c  = (int*)(ws + 151800000);                       // 400,000
  int* rs_b  = (int*)(ws + 152200000);                       // 200,000
  int* bsum_w = (int*)(ws + 152400000);                      // 4,096
  int* bsum_c = (int*)(ws + 152404096);                      // 4,096
  int* bsum_b = (int*)(ws + 152408192);                      // 4,096
  unsigned short* wf = (unsigned short*)(ws + 152412288);    // 245,760
  unsigned int* tmp_w = (unsigned int*)(ws + 152660000);     // 3,200,000
  unsigned int* tmp_c = (unsigned int*)(ws + 155860000);     // 3,200,000
  unsigned int* tmp_b = (unsigned int*)(ws + 159060000);     // 3,200,000
  // bh/bhs carved from S_w region (dead until first gather, which is after p2cvt)
  int* bh_w  = (int*)(ws + 76800000);
  int* bh_c  = (int*)(ws + 77110000);
  int* bh_b  = (int*)(ws + 77420000);
  int* bhs_w = (int*)(ws + 77580000);
  int* bhs_c = (int*)(ws + 77890000);
  int* bhs_b = (int*)(ws + 78200000);

  unsigned short* WF[10];
  size_t off = 0;
  for (int i = 0; i < 10; ++i) {
    WF[i] = wf + off;
    off += (i < 5) ? (size_t)128 * 128 : (size_t)128 * 64;
  }

  float* outP = (float*)d_out;              // 100000 x 64 fp32
  float* outA = outP + (size_t)NP * 64;     // 50000 x 64 fp32

  const int gP = (NP + 63) / 64, gA = (NA + 63) / 64;  // 1563, 782
  const int gG = (NP + 15) / 16;                       // 6250

  // ---- radix CSR args ----
  R3Args ra;
  ra.src[0] = wsrc; ra.dst[0] = wdst; ra.E[0] = Ew; ra.N[0] = NP;
  ra.src[1] = csrc; ra.dst[1] = cdst; ra.E[1] = Ec; ra.N[1] = NP;
  ra.src[2] = bsrc; ra.dst[2] = bdst; ra.E[2] = Eb; ra.N[2] = NA;
  ra.bh[0] = bh_w; ra.bh[1] = bh_c; ra.bh[2] = bh_b;
  ra.bhs[0] = bhs_w; ra.bhs[1] = bhs_c; ra.bhs[2] = bhs_b;
  ra.tmp[0] = tmp_w; ra.tmp[1] = tmp_c; ra.tmp[2] = tmp_b;
  ra.bkt[0] = bkt_w; ra.bkt[1] = bkt_c; ra.bkt[2] = bkt_b;
  ra.cnt[0] = cnt_w; ra.cnt[1] = cnt_c; ra.cnt[2] = cnt_b;
  ra.rs[0] = rs_w; ra.rs[1] = rs_c; ra.rs[2] = rs_b;
  int gSX = 0, gSC = 0, maxbin = 0;
  for (int y = 0; y < 3; ++y) {
    ra.nbin[y] = (ra.N[y] + 255) >> 8;
    ra.NB[y] = (ra.E[y] + EPB - 1) / EPB;
    if (ra.NB[y] > gSX) gSX = ra.NB[y];
    if (ra.nbin[y] > maxbin) maxbin = ra.nbin[y];
  }
  S3Args sa;
  sa.bsum[0] = bsum_w; sa.bsum[1] = bsum_c; sa.bsum[2] = bsum_b;
  for (int y = 0; y < 3; ++y) {
    sa.cnt[y] = ra.bh[y]; sa.rs[y] = ra.bhs[y];
    sa.n[y] = ra.nbin[y] * ra.NB[y];
    sa.nb[y] = (sa.n[y] + 1023) / 1024;
    if (sa.nb[y] > gSC) gSC = sa.nb[y];
  }

  // ---- merged p2 + warrange + cvt args ----
  const int n4p = NP * DI / 4, n4a = NA * DI / 4;
  P2CArgs pc;
  pc.ra = ra;
  const float* wsrcs[10] = {w1w, w1c, w1wb, w1rp, w1ra, w2w, w2c, w2wb, w2rp, w2ra};
  for (int i = 0; i < 10; ++i) { pc.wa.w[i] = wsrcs[i]; pc.wa.wf[i] = WF[i]; }
  pc.Xp = xp; pc.Yp = xpb; pc.n4p = n4p;
  pc.Xa = xa; pc.Ya = xab; pc.n4a = n4a;
  pc.maxbin = maxbin;
  pc.p2Blocks = 3 * maxbin;
  const int gPC = pc.p2Blocks + 80 + (n4p + n4a + 255) / 256;

  G3Args g1, g2;
  for (int i = 0; i < 3; ++i) {
    g1.cnt[i] = g2.cnt[i] = (i == 0) ? cnt_w : (i == 1) ? cnt_c : cnt_b;
    g1.rs[i]  = g2.rs[i]  = (i == 0) ? rs_w  : (i == 1) ? rs_c  : rs_b;
    g1.bkt[i] = g2.bkt[i] = (i == 0) ? bkt_w : (i == 1) ? bkt_c : bkt_b;
    g1.S[i]   = g2.S[i]   = (i == 0) ? S_w   : (i == 1) ? S_c   : S_b;
    g1.N[i]   = g2.N[i]   = (i == 2) ? NA : NP;
  }
  g1.X[0] = xab; g1.X[1] = xpb; g1.X[2] = xpb;
  g2.X[0] = ha;  g2.X[1] = hp;  g2.X[2] = hp;

  GemmPairArgs p1, p2;
  p1.A0[0] = xpb; p1.W0[0] = WF[3]; p1.A1[0] = S_w; p1.W1[0] = WF[0]; p1.A2 = S_c; p1.W2 = WF[1];
  p1.bias[0] = b1rp; p1.out[0] = hp; p1.N[0] = NP;
  p1.A0[1] = xab; p1.W0[1] = WF[4]; p1.A1[1] = S_b; p1.W1[1] = WF[2];
  p1.bias[1] = b1ra; p1.out[1] = ha; p1.N[1] = NA;
  p1.blocks0 = gP;
  p2.A0[0] = hp; p2.W0[0] = WF[8]; p2.A1[0] = S_w; p2.W1[0] = WF[5]; p2.A2 = S_c; p2.W2 = WF[6];
  p2.bias[0] = b2rp; p2.out[0] = outP; p2.N[0] = NP;
  p2.A0[1] = ha; p2.W0[1] = WF[9]; p2.A1[1] = S_b; p2.W1[1] = WF[7];
  p2.bias[1] = b2ra; p2.out[1] = outA; p2.N[1] = NA;
  p2.blocks0 = gP;

  // ---- CSR build + prep (no global atomics, no memsets) ----
  radix_s1_k<<<dim3(gSX, 3), 256, 0, stream>>>(ra);
  blocksum3_k<<<dim3(gSC, 3), 256, 0, stream>>>(sa);
  partials3_k<<<3, 256, 0, stream>>>(sa);
  scanwrite3_k<<<dim3(gSC, 3), 256, 0, stream>>>(sa);
  radix_x1_k<<<dim3(gSX, 3), 256, 0, stream>>>(ra);
  p2cvt_k<<<gPC, 256, 0, stream>>>(pc);   // p2 + weight rearrange + bf16 cvt

  // ---- layer 1 ----
  gather3_k<<<dim3(gG, 3), 256, 0, stream>>>(g1);
  gemm_pair_k<128, true, true><<<gP + gA, 256, 0, stream>>>(p1);

  // ---- layer 2 ----
  gather3_k<<<dim3(gG, 3), 256, 0, stream>>>(g2);
  gemm_pair_k<64, false, false><<<gP + gA, 256, 0, stream>>>(p2);
}